// Round 9
// baseline (357.938 us; speedup 1.0000x reference)
//
#include <hip/hip_runtime.h>

typedef unsigned short u16;
typedef __bf16 bf16x8 __attribute__((ext_vector_type(8)));
typedef float f32x4 __attribute__((ext_vector_type(4)));
typedef unsigned short u16x4 __attribute__((ext_vector_type(4)));

#define MFMA_B16(a, b, c) __builtin_amdgcn_mfma_f32_16x16x32_bf16((a), (b), (c), 0, 0, 0)

// ---------- helpers ----------
__device__ __forceinline__ u16 f2bf(float f) {
  unsigned int u = __float_as_uint(f);
  u += 0x7FFFu + ((u >> 16) & 1u);   // RNE
  return (u16)(u >> 16);
}

__device__ __forceinline__ u16x4 f4_to_bf4(float4 v) {
  u16x4 r;
  r[0] = f2bf(v.x); r[1] = f2bf(v.y); r[2] = f2bf(v.z); r[3] = f2bf(v.w);
  return r;
}

// ---------- f32 -> bf16 converts ----------
__global__ __launch_bounds__(256) void cvt3(const float* __restrict__ a,
                                            const float* __restrict__ b,
                                            const float* __restrict__ c,
                                            u16* __restrict__ dst, int n4, int n) {
  int i = blockIdx.x * 256 + threadIdx.x;
  int stride = gridDim.x * 256;
  const float4* a4 = (const float4*)a;
  const float4* b4 = (const float4*)b;
  const float4* c4 = (const float4*)c;
  u16x4* d0 = (u16x4*)dst;
  u16x4* d1 = (u16x4*)(dst + (size_t)n);
  u16x4* d2 = (u16x4*)(dst + (size_t)2 * n);
  for (; i < n4; i += stride) {
    d0[i] = f4_to_bf4(a4[i]);
    d1[i] = f4_to_bf4(b4[i]);
    d2[i] = f4_to_bf4(c4[i]);
  }
}

__global__ __launch_bounds__(256) void cvtW(const float* __restrict__ a,
                                            const float* __restrict__ b,
                                            const float* __restrict__ c,
                                            const float* __restrict__ d,
                                            u16* __restrict__ dst, int n4, int n) {
  int i = blockIdx.x * 256 + threadIdx.x;
  int stride = gridDim.x * 256;
  const float4* a4 = (const float4*)a;
  const float4* b4 = (const float4*)b;
  const float4* c4 = (const float4*)c;
  const float4* d4 = (const float4*)d;
  u16x4* o0 = (u16x4*)dst;
  u16x4* o1 = (u16x4*)(dst + (size_t)n);
  u16x4* o2 = (u16x4*)(dst + (size_t)2 * n);
  u16x4* o3 = (u16x4*)(dst + (size_t)3 * n);
  for (; i < n4; i += stride) {
    o0[i] = f4_to_bf4(a4[i]);
    o1[i] = f4_to_bf4(b4[i]);
    o2[i] = f4_to_bf4(c4[i]);
    o3[i] = f4_to_bf4(d4[i]);
  }
}

// ---------- B-transposed bf16 GEMM: C[M,512] = A[M,512] * Bw[512,512]^T ----------
template <bool OUT_F32>
__device__ __forceinline__ void gemm_body(const u16* __restrict__ A,
                                          const u16* __restrict__ Bw,
                                          u16* __restrict__ Cb, float* __restrict__ Cf,
                                          int bm, int bn) {
  __shared__ __align__(16) u16 As[128][40];
  __shared__ __align__(16) u16 Bs[128][40];
  const int tid = threadIdx.x;
  const int wave = tid >> 6, lane = tid & 63;
  const int g = lane >> 4, l16 = lane & 15;
  const int wr = (wave >> 1) * 64, wc = (wave & 1) * 64;
  const int srow = tid >> 1, scol = (tid & 1) * 16;
  const u16* Ar = A + (size_t)(bm + srow) * 512 + scol;
  const u16* Br = Bw + (size_t)(bn + srow) * 512 + scol;
  f32x4 acc[4][4] = {};
  for (int k0 = 0; k0 < 512; k0 += 32) {
    *(uint4*)(&As[srow][scol])     = *(const uint4*)(Ar + k0);
    *(uint4*)(&As[srow][scol + 8]) = *(const uint4*)(Ar + k0 + 8);
    *(uint4*)(&Bs[srow][scol])     = *(const uint4*)(Br + k0);
    *(uint4*)(&Bs[srow][scol + 8]) = *(const uint4*)(Br + k0 + 8);
    __syncthreads();
    bf16x8 af[4], bfr[4];
#pragma unroll
    for (int i = 0; i < 4; ++i) af[i] = *(const bf16x8*)(&As[wr + i * 16 + l16][g * 8]);
#pragma unroll
    for (int j = 0; j < 4; ++j) bfr[j] = *(const bf16x8*)(&Bs[wc + j * 16 + l16][g * 8]);
#pragma unroll
    for (int i = 0; i < 4; ++i)
#pragma unroll
      for (int j = 0; j < 4; ++j)
        acc[i][j] = MFMA_B16(af[i], bfr[j], acc[i][j]);
    __syncthreads();
  }
#pragma unroll
  for (int i = 0; i < 4; ++i)
#pragma unroll
    for (int j = 0; j < 4; ++j)
#pragma unroll
      for (int r = 0; r < 4; ++r) {
        int row = bm + wr + i * 16 + g * 4 + r;
        int col = bn + wc + j * 16 + l16;
        if constexpr (OUT_F32)
          Cf[(size_t)row * 512 + col] = acc[i][j][r];
        else
          Cb[(size_t)row * 512 + col] = f2bf(acc[i][j][r]);
      }
}

__global__ __launch_bounds__(256) void gemm_qkv(const u16* __restrict__ Xbf,
                                                const u16* __restrict__ Wbf,
                                                u16* __restrict__ QKVp) {
  int z = blockIdx.z;
  gemm_body<false>(Xbf + (size_t)z * 4194304, Wbf + (size_t)z * 262144,
                   QKVp + (size_t)z * 4194304, nullptr,
                   blockIdx.x * 128, blockIdx.y * 128);
}

__global__ __launch_bounds__(256) void gemm_f32out(const u16* __restrict__ A,
                                                   const u16* __restrict__ Bw,
                                                   float* __restrict__ C) {
  gemm_body<true>(A, Bw, nullptr, C, blockIdx.x * 128, blockIdx.y * 128);
}

// ---------- V transpose: Vp[b][s][d] (bf16) -> Vt[b][d][s] (bf16) ----------
__global__ __launch_bounds__(256) void transpose_v(const u16* __restrict__ Vp,
                                                   u16* __restrict__ Vt) {
  __shared__ __align__(16) u16 t[64][72];
  const int b = blockIdx.z;
  const int s0 = blockIdx.x * 64, d0 = blockIdx.y * 64;
  const u16* in = Vp + (size_t)b * 2048 * 512;
  u16* outp = Vt + (size_t)b * 512 * 2048;
  const int tid = threadIdx.x;
  const int r = tid >> 2;
  const int c = (tid & 3) * 16;
  const uint4* src = (const uint4*)(in + (size_t)(s0 + r) * 512 + d0 + c);
  uint4 v0 = src[0], v1 = src[1];
  *(uint4*)(&t[r][c]) = v0;
  *(uint4*)(&t[r][c + 8]) = v1;
  __syncthreads();
  u16 tmp[16];
#pragma unroll
  for (int j = 0; j < 16; ++j) tmp[j] = t[c + j][r];
  uint4* dst = (uint4*)(outp + (size_t)(d0 + r) * 2048 + s0 + c);
  dst[0] = *(uint4*)(&tmp[0]);
  dst[1] = *(uint4*)(&tmp[8]);
}

// ---------- lsum kernel: invl[bh][q] = 1 / sum_k exp(q.k/8) ----------
__global__ __launch_bounds__(256) void lsum_kernel(const u16* __restrict__ Qp,
                                                   const u16* __restrict__ Kp,
                                                   float* __restrict__ invl) {
  const int wave = threadIdx.x >> 6, lane = threadIdx.x & 63;
  const int g = lane >> 4, l16 = lane & 15;
  const int bx = blockIdx.x;
  const int xcd = bx & 7;
  const int j = bx >> 3;                  // 0..127
  const int bh = xcd * 4 + (j & 3);
  const int qg = 127 - ((j >> 2) * 4 + wave);   // heavy-first
  const int b = bh >> 3, h = bh & 7;
  const u16* Qh = Qp + (size_t)b * 1048576 + h * 64;
  const u16* Kh = Kp + (size_t)b * 1048576 + h * 64;
  const int qrow = qg * 16 + l16;
  bf16x8 q0 = *(const bf16x8*)(Qh + (size_t)qrow * 512 + g * 8);
  bf16x8 q1 = *(const bf16x8*)(Qh + (size_t)qrow * 512 + 32 + g * 8);
  float lsum = 0.f;
  for (int kt = 0; kt < qg; ++kt) {
    const u16* Krow = Kh + (size_t)(kt * 16 + l16) * 512;
    bf16x8 k0 = *(const bf16x8*)(Krow + g * 8);
    bf16x8 k1 = *(const bf16x8*)(Krow + 32 + g * 8);
    f32x4 c = {0.f, 0.f, 0.f, 0.f};
    c = MFMA_B16(k0, q0, c);
    c = MFMA_B16(k1, q1, c);
    lsum += __expf(c[0] * 0.125f) + __expf(c[1] * 0.125f)
          + __expf(c[2] * 0.125f) + __expf(c[3] * 0.125f);
  }
  {  // diagonal chunk
    const u16* Krow = Kh + (size_t)(qg * 16 + l16) * 512;
    bf16x8 k0 = *(const bf16x8*)(Krow + g * 8);
    bf16x8 k1 = *(const bf16x8*)(Krow + 32 + g * 8);
    f32x4 c = {0.f, 0.f, 0.f, 0.f};
    c = MFMA_B16(k0, q0, c);
    c = MFMA_B16(k1, q1, c);
    const int kbase = qg * 16 + g * 4;
#pragma unroll
    for (int r = 0; r < 4; ++r)
      lsum += (kbase + r > qrow) ? 0.f : __expf(c[r] * 0.125f);
  }
  lsum += __shfl_xor(lsum, 16);
  lsum += __shfl_xor(lsum, 32);
  if (lane < 16) invl[(size_t)bh * 2048 + qrow] = 1.f / lsum;
}

// ---------- fused causal attention, v8 (paired + single-K-buffer + 3 blocks/CU) ----------
// 512 blocks x 256 thr. Block = (bh, strip-pair {p, 31-p}); bh pinned to XCD.
// Single 16KB K LDS buffer; next tile prefetched into 16 VGPRs (T14) and
// ds-written after the read barrier. LDS 48KB -> 3 blocks/CU (12 waves/CU).
__global__ __launch_bounds__(256, 3) void attn_kernel(const u16* __restrict__ Qp,
                                                      const u16* __restrict__ Kp,
                                                      const u16* __restrict__ Vt,
                                                      const float* __restrict__ invl,
                                                      float* __restrict__ attn_all,
                                                      u16* __restrict__ ctx) {
  __shared__ __align__(16) u16 Ks[8192];             // 16KB, chunk-swizzled
  __shared__ __align__(16) u16 Plds[4][2][16][128];  // 32KB
  const int tid = threadIdx.x;
  const int wave = tid >> 6, lane = tid & 63;
  const int g = lane >> 4, l16 = lane & 15;
  const int id = blockIdx.x;
  const int r8 = id >> 3;
  const int bh = (id & 7) * 4 + (r8 & 3);
  const int pair = r8 >> 2;
  const int sLo = pair, sHi = 31 - pair;
  const int b = bh >> 3, h = bh & 7;
  const int nktH = sHi / 2 + 1, nktL = sLo / 2 + 1;
  const char* KhB = (const char*)Kp + (size_t)b * 2097152 + h * 128;
  const char* VhB = (const char*)Vt + ((size_t)b * 512 + h * 64) * 4096;
  const u16* Qh = Qp + (size_t)b * 1048576 + h * 64;
  float* attn = attn_all + (size_t)bh * 4194304;
  char* KsC = (char*)Ks;
  char* PwH = (char*)&Plds[wave][0][0][0];
  char* PwL = (char*)&Plds[wave][1][0][0];
  const int swk = (l16 & 7) << 4;

  const int sr_r = tid >> 3;
  const int sr_c = tid & 7;
  const size_t sr_src = (size_t)sr_r * 1024 + sr_c * 16;
  const int sr_dst = sr_r * 128 + (((sr_c ^ (sr_r & 7))) << 4);
  uint4 sr[4];

#define STAGE_LOAD(KT)                                                         \
  { _Pragma("unroll") for (int jj = 0; jj < 4; ++jj)                           \
      sr[jj] = *(const uint4*)(KhB + (size_t)(KT) * 131072 + (size_t)jj * 32768 + sr_src); }
#define STAGE_WRITE()                                                          \
  { _Pragma("unroll") for (int jj = 0; jj < 4; ++jj)                           \
      *(uint4*)(KsC + jj * 4096 + sr_dst) = sr[jj]; }
// Raw-barrier pair: no vmcnt(0) drain -> nt stores pipeline across k-tiles.
#define BAR_READS_DONE()                                                       \
  { asm volatile("" ::: "memory");                                             \
    __builtin_amdgcn_s_barrier();                                              \
    __builtin_amdgcn_sched_barrier(0); }
#define BAR_WRITES_VISIBLE()                                                   \
  { asm volatile("s_waitcnt lgkmcnt(0)" ::: "memory");                         \
    __builtin_amdgcn_sched_barrier(0);                                         \
    __builtin_amdgcn_s_barrier();                                              \
    __builtin_amdgcn_sched_barrier(0); }

  const int qrH = sHi * 64 + wave * 16;
  const int qrL = sLo * 64 + wave * 16;
  const int qrowH = qrH + l16, qrowL = qrL + l16;

  bf16x8 qH0 = *(const bf16x8*)(Qh + (size_t)qrowH * 512 + g * 8);
  bf16x8 qH1 = *(const bf16x8*)(Qh + (size_t)qrowH * 512 + 32 + g * 8);
  bf16x8 qL0 = *(const bf16x8*)(Qh + (size_t)qrowL * 512 + g * 8);
  bf16x8 qL1 = *(const bf16x8*)(Qh + (size_t)qrowL * 512 + 32 + g * 8);

  const float invH = invl[(size_t)bh * 2048 + qrowH];
  const float invL = invl[(size_t)bh * 2048 + qrowL];

  f32x4 oaccH[4] = {}, oaccL[4] = {};
  {
    STAGE_LOAD(0); STAGE_WRITE();
    if (nktH > 1) STAGE_LOAD(1);       // prefetch next tile into registers
    BAR_WRITES_VISIBLE();
    for (int kt = 0; kt < nktH; ++kt) {
      const int ktb = kt * 128;
      const bool doL = (kt < nktL);
      const bool dH = (kt == nktH - 1), dL = (kt == nktL - 1);
#pragma unroll
      for (int kf = 0; kf < 8; ++kf) {
        const int ro = (kf * 16 + l16) * 128;
        bf16x8 ka = *(const bf16x8*)(KsC + ro + ((g ^ (l16 & 7)) << 4));
        bf16x8 kb = *(const bf16x8*)(KsC + ro + (((4 + g) ^ (l16 & 7)) << 4));
        const int kbase = ktb + kf * 16 + g * 4;
        f32x4 cH = {0.f, 0.f, 0.f, 0.f};
        __builtin_amdgcn_s_setprio(1);
        cH = MFMA_B16(ka, qH0, cH);
        cH = MFMA_B16(kb, qH1, cH);
        __builtin_amdgcn_s_setprio(0);
        {
          float p[4];
#pragma unroll
          for (int r = 0; r < 4; ++r) {
            float e = __expf(cH[r] * 0.125f) * invH;
            p[r] = (dH && (kbase + r > qrowH)) ? 0.f : e;
          }
          unsigned lo = (unsigned)f2bf(p[0]) | ((unsigned)f2bf(p[1]) << 16);
          unsigned hi = (unsigned)f2bf(p[2]) | ((unsigned)f2bf(p[3]) << 16);
          *(uint2*)(PwH + l16 * 256 + ((kf * 32 + g * 8) ^ swk)) = make_uint2(lo, hi);
        }
        if (doL) {
          f32x4 cL = {0.f, 0.f, 0.f, 0.f};
          __builtin_amdgcn_s_setprio(1);
          cL = MFMA_B16(ka, qL0, cL);
          cL = MFMA_B16(kb, qL1, cL);
          __builtin_amdgcn_s_setprio(0);
          float p[4];
#pragma unroll
          for (int r = 0; r < 4; ++r) {
            float e = __expf(cL[r] * 0.125f) * invL;
            p[r] = (dL && (kbase + r > qrowL)) ? 0.f : e;
          }
          unsigned lo = (unsigned)f2bf(p[0]) | ((unsigned)f2bf(p[1]) << 16);
          unsigned hi = (unsigned)f2bf(p[2]) | ((unsigned)f2bf(p[3]) << 16);
          *(uint2*)(PwL + l16 * 256 + ((kf * 32 + g * 8) ^ swk)) = make_uint2(lo, hi);
        }
      }
      // PV (V loads shared by both strips)
#pragma unroll
      for (int kb4 = 0; kb4 < 4; ++kb4) {
        bf16x8 paH = *(const bf16x8*)(PwH + l16 * 256 + ((kb4 * 64 + g * 16) ^ swk));
        bf16x8 paL;
        if (doL) paL = *(const bf16x8*)(PwL + l16 * 256 + ((kb4 * 64 + g * 16) ^ swk));
#pragma unroll
        for (int cn = 0; cn < 4; ++cn) {
          bf16x8 vb = *(const bf16x8*)(VhB + (size_t)(cn * 16 + l16) * 4096 +
                                       (ktb + kb4 * 32 + g * 8) * 2);
          __builtin_amdgcn_s_setprio(1);
          oaccH[cn] = MFMA_B16(paH, vb, oaccH[cn]);
          if (doL) oaccL[cn] = MFMA_B16(paL, vb, oaccL[cn]);
          __builtin_amdgcn_s_setprio(0);
        }
      }
      // attn nt-stores: 2 rows x 512B contiguous per instruction
      {
        const int c32 = lane & 31;
        const int rh = lane >> 5;
#pragma unroll
        for (int i = 0; i < 8; ++i) {
          const int row = i * 2 + rh;
          uint2 pk = *(const uint2*)(PwH + row * 256 + ((c32 * 8) ^ ((row & 7) << 4)));
          f32x4 o;
          o[0] = __uint_as_float(pk.x << 16);
          o[1] = __uint_as_float(pk.x & 0xffff0000u);
          o[2] = __uint_as_float(pk.y << 16);
          o[3] = __uint_as_float(pk.y & 0xffff0000u);
          __builtin_nontemporal_store(o, (f32x4*)(&attn[(size_t)(qrH + row) * 2048 + ktb + c32 * 4]));
        }
        if (doL) {
#pragma unroll
          for (int i = 0; i < 8; ++i) {
            const int row = i * 2 + rh;
            uint2 pk = *(const uint2*)(PwL + row * 256 + ((c32 * 8) ^ ((row & 7) << 4)));
            f32x4 o;
            o[0] = __uint_as_float(pk.x << 16);
            o[1] = __uint_as_float(pk.x & 0xffff0000u);
            o[2] = __uint_as_float(pk.y << 16);
            o[3] = __uint_as_float(pk.y & 0xffff0000u);
            __builtin_nontemporal_store(o, (f32x4*)(&attn[(size_t)(qrL + row) * 2048 + ktb + c32 * 4]));
          }
        }
      }
      if (kt + 1 < nktH) {
        BAR_READS_DONE();                // all waves done reading Ks
        STAGE_WRITE();                   // next tile from prefetch registers
        if (kt + 2 < nktH) STAGE_LOAD(kt + 2);
        BAR_WRITES_VISIBLE();            // lgkmcnt(0)+barrier; nt stores stay in flight
      }
    }
  }

  // ctx writes
  u16* cb = ctx + (size_t)b * 1048576 + h * 64;
#pragma unroll
  for (int cn = 0; cn < 4; ++cn)
#pragma unroll
    for (int r = 0; r < 4; ++r) {
      cb[(size_t)(qrH + g * 4 + r) * 512 + cn * 16 + l16] = f2bf(oaccH[cn][r]);
      cb[(size_t)(qrL + g * 4 + r) * 512 + cn * 16 + l16] = f2bf(oaccL[cn][r]);
    }

  // zero-fill strictly-upper tails (nt stores)
  f32x4 z4 = {0.f, 0.f, 0.f, 0.f};
#pragma unroll
  for (int s2 = 0; s2 < 2; ++s2) {
    const int base = s2 ? sLo * 64 : sHi * 64;
    const int z0 = (s2 ? nktL : nktH) * 128;
    if (z0 < 2048) {
      for (int r = wave; r < 64; r += 4) {
        float* rowp = attn + (size_t)(base + r) * 2048;
        for (int c = z0 + lane * 4; c < 2048; c += 256)
          __builtin_nontemporal_store(z4, (f32x4*)(rowp + c));
      }
    }
  }
#undef STAGE_LOAD
#undef STAGE_WRITE
#undef BAR_READS_DONE
#undef BAR_WRITES_VISIBLE
}

// ---------- residual + LayerNorm ----------
__global__ __launch_bounds__(256) void ln_kernel(const float* __restrict__ proj,
                                                 const float* __restrict__ resid,
                                                 const float* __restrict__ gamma,
                                                 const float* __restrict__ beta,
                                                 float* __restrict__ out) {
  const int wave = threadIdx.x >> 6, lane = threadIdx.x & 63;
  const int row = blockIdx.x * 4 + wave;
  const float4* p4 = (const float4*)(proj + (size_t)row * 512);
  const float4* r4 = (const float4*)(resid + (size_t)row * 512);
  float4 a0 = p4[lane * 2], a1 = p4[lane * 2 + 1];
  float4 q0 = r4[lane * 2], q1 = r4[lane * 2 + 1];
  float x[8];
  x[0] = a0.x + q0.x; x[1] = a0.y + q0.y; x[2] = a0.z + q0.z; x[3] = a0.w + q0.w;
  x[4] = a1.x + q1.x; x[5] = a1.y + q1.y; x[6] = a1.z + q1.z; x[7] = a1.w + q1.w;
  float s = 0.f;
#pragma unroll
  for (int j = 0; j < 8; ++j) s += x[j];
#pragma unroll
  for (int d = 1; d < 64; d <<= 1) s += __shfl_xor(s, d);
  float mu = s * (1.f / 512.f);
  float v = 0.f;
#pragma unroll
  for (int j = 0; j < 8; ++j) { float t = x[j] - mu; v += t * t; }
#pragma unroll
  for (int d = 1; d < 64; d <<= 1) v += __shfl_xor(v, d);
  float rs = rsqrtf(v * (1.f / 512.f) + 1e-5f);
  const float4* g4 = (const float4*)gamma;
  const float4* b4 = (const float4*)beta;
  float4 g0 = g4[lane * 2], g1 = g4[lane * 2 + 1];
  float4 bb0 = b4[lane * 2], bb1 = b4[lane * 2 + 1];
  float4 y0, y1;
  y0.x = (x[0] - mu) * rs * g0.x + bb0.x;
  y0.y = (x[1] - mu) * rs * g0.y + bb0.y;
  y0.z = (x[2] - mu) * rs * g0.z + bb0.z;
  y0.w = (x[3] - mu) * rs * g0.w + bb0.w;
  y1.x = (x[4] - mu) * rs * g1.x + bb1.x;
  y1.y = (x[5] - mu) * rs * g1.y + bb1.y;
  y1.z = (x[6] - mu) * rs * g1.z + bb1.z;
  y1.w = (x[7] - mu) * rs * g1.w + bb1.w;
  float4* o4 = (float4*)(out + (size_t)row * 512);
  o4[lane * 2] = y0;
  o4[lane * 2 + 1] = y1;
}

// ---------- launch ----------
extern "C" void kernel_launch(void* const* d_in, const int* in_sizes, int n_in,
                              void* d_out, int out_size, void* d_ws, size_t ws_size,
                              hipStream_t stream) {
  (void)in_sizes; (void)n_in; (void)out_size; (void)ws_size;
  const float* inQ = (const float*)d_in[0];
  const float* inK = (const float*)d_in[1];
  const float* inV = (const float*)d_in[2];
  const float* Wq = (const float*)d_in[4];
  const float* Wk = (const float*)d_in[5];
  const float* Wv = (const float*)d_in[6];
  const float* Wo = (const float*)d_in[7];
  const float* gamma = (const float*)d_in[8];
  const float* beta = (const float*)d_in[9];

  float* out = (float*)d_out;
  float* attn = out + (size_t)4 * 2048 * 512;

  char* ws = (char*)d_ws;
  u16* Qp  = (u16*)(ws + 0);
  u16* Kp  = (u16*)(ws + 8388608);
  u16* Vp  = (u16*)(ws + 16777216);      // freed after transpose_v -> reused for invl
  u16* Vt  = (u16*)(ws + 25165824);
  u16* ctx = (u16*)(ws + 33554432);
  u16* Wbf = (u16*)(ws + 41943040);
  float* invl = (float*)(ws + 16777216); // 256 KB, overlaps dead Vp
  float* proj = (float*)(ws + 0);        // reuses Qp+Kp after attention
  u16* Xbf = (u16*)attn;

  cvt3<<<2048, 256, 0, stream>>>(inQ, inK, inV, Xbf, 1048576, 4194304);
  cvtW<<<256, 256, 0, stream>>>(Wq, Wk, Wv, Wo, Wbf, 65536, 262144);
  gemm_qkv<<<dim3(64, 4, 3), 256, 0, stream>>>(Xbf, Wbf, Qp);
  transpose_v<<<dim3(32, 8, 4), 256, 0, stream>>>(Vp, Vt);
  lsum_kernel<<<1024, 256, 0, stream>>>(Qp, Kp, invl);
  attn_kernel<<<dim3(512), 256, 0, stream>>>(Qp, Kp, Vt, invl, attn, ctx);
  gemm_f32out<<<dim3(64, 4, 1), 256, 0, stream>>>(ctx, Wbf + (size_t)3 * 262144, proj);
  ln_kernel<<<2048, 256, 0, stream>>>(proj, inQ, gamma, beta, out);
}

// Round 10
// 339.172 us; speedup vs baseline: 1.0553x; 1.0553x over previous
//
#include <hip/hip_runtime.h>

typedef unsigned short u16;
typedef __bf16 bf16x8 __attribute__((ext_vector_type(8)));
typedef float f32x4 __attribute__((ext_vector_type(4)));
typedef unsigned short u16x4 __attribute__((ext_vector_type(4)));

#define MFMA_B16(a, b, c) __builtin_amdgcn_mfma_f32_16x16x32_bf16((a), (b), (c), 0, 0, 0)

// ---------- helpers ----------
__device__ __forceinline__ u16 f2bf(float f) {
  unsigned int u = __float_as_uint(f);
  u += 0x7FFFu + ((u >> 16) & 1u);   // RNE
  return (u16)(u >> 16);
}

__device__ __forceinline__ u16x4 f4_to_bf4(float4 v) {
  u16x4 r;
  r[0] = f2bf(v.x); r[1] = f2bf(v.y); r[2] = f2bf(v.z); r[3] = f2bf(v.w);
  return r;
}

// ---------- f32 -> bf16 converts ----------
__global__ __launch_bounds__(256) void cvt3(const float* __restrict__ a,
                                            const float* __restrict__ b,
                                            const float* __restrict__ c,
                                            u16* __restrict__ dst, int n4, int n) {
  int i = blockIdx.x * 256 + threadIdx.x;
  int stride = gridDim.x * 256;
  const float4* a4 = (const float4*)a;
  const float4* b4 = (const float4*)b;
  const float4* c4 = (const float4*)c;
  u16x4* d0 = (u16x4*)dst;
  u16x4* d1 = (u16x4*)(dst + (size_t)n);
  u16x4* d2 = (u16x4*)(dst + (size_t)2 * n);
  for (; i < n4; i += stride) {
    d0[i] = f4_to_bf4(a4[i]);
    d1[i] = f4_to_bf4(b4[i]);
    d2[i] = f4_to_bf4(c4[i]);
  }
}

__global__ __launch_bounds__(256) void cvtW(const float* __restrict__ a,
                                            const float* __restrict__ b,
                                            const float* __restrict__ c,
                                            const float* __restrict__ d,
                                            u16* __restrict__ dst, int n4, int n) {
  int i = blockIdx.x * 256 + threadIdx.x;
  int stride = gridDim.x * 256;
  const float4* a4 = (const float4*)a;
  const float4* b4 = (const float4*)b;
  const float4* c4 = (const float4*)c;
  const float4* d4 = (const float4*)d;
  u16x4* o0 = (u16x4*)dst;
  u16x4* o1 = (u16x4*)(dst + (size_t)n);
  u16x4* o2 = (u16x4*)(dst + (size_t)2 * n);
  u16x4* o3 = (u16x4*)(dst + (size_t)3 * n);
  for (; i < n4; i += stride) {
    o0[i] = f4_to_bf4(a4[i]);
    o1[i] = f4_to_bf4(b4[i]);
    o2[i] = f4_to_bf4(c4[i]);
    o3[i] = f4_to_bf4(d4[i]);
  }
}

// ---------- B-transposed bf16 GEMM: C[M,512] = A[M,512] * Bw[512,512]^T ----------
template <bool OUT_F32>
__device__ __forceinline__ void gemm_body(const u16* __restrict__ A,
                                          const u16* __restrict__ Bw,
                                          u16* __restrict__ Cb, float* __restrict__ Cf,
                                          int bm, int bn) {
  __shared__ __align__(16) u16 As[128][40];
  __shared__ __align__(16) u16 Bs[128][40];
  const int tid = threadIdx.x;
  const int wave = tid >> 6, lane = tid & 63;
  const int g = lane >> 4, l16 = lane & 15;
  const int wr = (wave >> 1) * 64, wc = (wave & 1) * 64;
  const int srow = tid >> 1, scol = (tid & 1) * 16;
  const u16* Ar = A + (size_t)(bm + srow) * 512 + scol;
  const u16* Br = Bw + (size_t)(bn + srow) * 512 + scol;
  f32x4 acc[4][4] = {};
  for (int k0 = 0; k0 < 512; k0 += 32) {
    *(uint4*)(&As[srow][scol])     = *(const uint4*)(Ar + k0);
    *(uint4*)(&As[srow][scol + 8]) = *(const uint4*)(Ar + k0 + 8);
    *(uint4*)(&Bs[srow][scol])     = *(const uint4*)(Br + k0);
    *(uint4*)(&Bs[srow][scol + 8]) = *(const uint4*)(Br + k0 + 8);
    __syncthreads();
    bf16x8 af[4], bfr[4];
#pragma unroll
    for (int i = 0; i < 4; ++i) af[i] = *(const bf16x8*)(&As[wr + i * 16 + l16][g * 8]);
#pragma unroll
    for (int j = 0; j < 4; ++j) bfr[j] = *(const bf16x8*)(&Bs[wc + j * 16 + l16][g * 8]);
#pragma unroll
    for (int i = 0; i < 4; ++i)
#pragma unroll
      for (int j = 0; j < 4; ++j)
        acc[i][j] = MFMA_B16(af[i], bfr[j], acc[i][j]);
    __syncthreads();
  }
#pragma unroll
  for (int i = 0; i < 4; ++i)
#pragma unroll
    for (int j = 0; j < 4; ++j)
#pragma unroll
      for (int r = 0; r < 4; ++r) {
        int row = bm + wr + i * 16 + g * 4 + r;
        int col = bn + wc + j * 16 + l16;
        if constexpr (OUT_F32)
          Cf[(size_t)row * 512 + col] = acc[i][j][r];
        else
          Cb[(size_t)row * 512 + col] = f2bf(acc[i][j][r]);
      }
}

__global__ __launch_bounds__(256) void gemm_qkv(const u16* __restrict__ Xbf,
                                                const u16* __restrict__ Wbf,
                                                u16* __restrict__ QKVp) {
  int z = blockIdx.z;
  gemm_body<false>(Xbf + (size_t)z * 4194304, Wbf + (size_t)z * 262144,
                   QKVp + (size_t)z * 4194304, nullptr,
                   blockIdx.x * 128, blockIdx.y * 128);
}

__global__ __launch_bounds__(256) void gemm_f32out(const u16* __restrict__ A,
                                                   const u16* __restrict__ Bw,
                                                   float* __restrict__ C) {
  gemm_body<true>(A, Bw, nullptr, C, blockIdx.x * 128, blockIdx.y * 128);
}

// ---------- V transpose: Vp[b][s][d] (bf16) -> Vt[b][d][s] (bf16) ----------
__global__ __launch_bounds__(256) void transpose_v(const u16* __restrict__ Vp,
                                                   u16* __restrict__ Vt) {
  __shared__ __align__(16) u16 t[64][72];
  const int b = blockIdx.z;
  const int s0 = blockIdx.x * 64, d0 = blockIdx.y * 64;
  const u16* in = Vp + (size_t)b * 2048 * 512;
  u16* outp = Vt + (size_t)b * 512 * 2048;
  const int tid = threadIdx.x;
  const int r = tid >> 2;
  const int c = (tid & 3) * 16;
  const uint4* src = (const uint4*)(in + (size_t)(s0 + r) * 512 + d0 + c);
  uint4 v0 = src[0], v1 = src[1];
  *(uint4*)(&t[r][c]) = v0;
  *(uint4*)(&t[r][c + 8]) = v1;
  __syncthreads();
  u16 tmp[16];
#pragma unroll
  for (int j = 0; j < 16; ++j) tmp[j] = t[c + j][r];
  uint4* dst = (uint4*)(outp + (size_t)(d0 + r) * 2048 + s0 + c);
  dst[0] = *(uint4*)(&tmp[0]);
  dst[1] = *(uint4*)(&tmp[8]);
}

// ---------- lsum kernel: invl[bh][q] = 1 / sum_k exp(q.k/8) ----------
__global__ __launch_bounds__(256) void lsum_kernel(const u16* __restrict__ Qp,
                                                   const u16* __restrict__ Kp,
                                                   float* __restrict__ invl) {
  const int wave = threadIdx.x >> 6, lane = threadIdx.x & 63;
  const int g = lane >> 4, l16 = lane & 15;
  const int bx = blockIdx.x;
  const int xcd = bx & 7;
  const int j = bx >> 3;                  // 0..127
  const int bh = xcd * 4 + (j & 3);
  const int qg = 127 - ((j >> 2) * 4 + wave);   // heavy-first
  const int b = bh >> 3, h = bh & 7;
  const u16* Qh = Qp + (size_t)b * 1048576 + h * 64;
  const u16* Kh = Kp + (size_t)b * 1048576 + h * 64;
  const int qrow = qg * 16 + l16;
  bf16x8 q0 = *(const bf16x8*)(Qh + (size_t)qrow * 512 + g * 8);
  bf16x8 q1 = *(const bf16x8*)(Qh + (size_t)qrow * 512 + 32 + g * 8);
  float lsum = 0.f;
  for (int kt = 0; kt < qg; ++kt) {
    const u16* Krow = Kh + (size_t)(kt * 16 + l16) * 512;
    bf16x8 k0 = *(const bf16x8*)(Krow + g * 8);
    bf16x8 k1 = *(const bf16x8*)(Krow + 32 + g * 8);
    f32x4 c = {0.f, 0.f, 0.f, 0.f};
    c = MFMA_B16(k0, q0, c);
    c = MFMA_B16(k1, q1, c);
    lsum += __expf(c[0] * 0.125f) + __expf(c[1] * 0.125f)
          + __expf(c[2] * 0.125f) + __expf(c[3] * 0.125f);
  }
  {  // diagonal chunk
    const u16* Krow = Kh + (size_t)(qg * 16 + l16) * 512;
    bf16x8 k0 = *(const bf16x8*)(Krow + g * 8);
    bf16x8 k1 = *(const bf16x8*)(Krow + 32 + g * 8);
    f32x4 c = {0.f, 0.f, 0.f, 0.f};
    c = MFMA_B16(k0, q0, c);
    c = MFMA_B16(k1, q1, c);
    const int kbase = qg * 16 + g * 4;
#pragma unroll
    for (int r = 0; r < 4; ++r)
      lsum += (kbase + r > qrow) ? 0.f : __expf(c[r] * 0.125f);
  }
  lsum += __shfl_xor(lsum, 16);
  lsum += __shfl_xor(lsum, 32);
  if (lane < 16) invl[(size_t)bh * 2048 + qrow] = 1.f / lsum;
}

// ---------- fused causal attention, v9: producer/consumer wave split ----------
// 512 blocks x 512 thr. Waves 0-3 COMPUTE (QK^T->exp->P(LDS)->PV, no global
// stores). Waves 4-7 STORE (read P[prev buf], widen to f32, nt-store stream).
// P double-buffered (2x32KB) so stores of tile kt-1 overlap compute of kt.
// K single 16KB buffer, rewritten in the PV phase (latency hidden by MFMA).
// LDS 80KB -> 2 blocks/CU = 8 compute + 8 store waves per CU.
__global__ __launch_bounds__(512, 4) void attn_kernel(const u16* __restrict__ Qp,
                                                      const u16* __restrict__ Kp,
                                                      const u16* __restrict__ Vt,
                                                      const float* __restrict__ invl,
                                                      float* __restrict__ attn_all,
                                                      u16* __restrict__ ctx) {
  __shared__ __align__(16) u16 Ks[8192];             // 16KB, chunk-swizzled
  __shared__ __align__(16) u16 Plds[2][4][2][16][128];  // 64KB: buf, pwave, strip, row
  const int tid = threadIdx.x;
  const int wave = tid >> 6, lane = tid & 63;
  const int g = lane >> 4, l16 = lane & 15;
  const bool producer = (wave < 4);
  const int pw = wave & 3;                 // producer id / consumer's target wave
  const int id = blockIdx.x;
  const int r8 = id >> 3;
  const int bh = (id & 7) * 4 + (r8 & 3);
  const int pair = r8 >> 2;
  const int sLo = pair, sHi = 31 - pair;
  const int b = bh >> 3, h = bh & 7;
  const int nktH = sHi / 2 + 1, nktL = sLo / 2 + 1;
  const char* KhB = (const char*)Kp + (size_t)b * 2097152 + h * 128;
  const char* VhB = (const char*)Vt + ((size_t)b * 512 + h * 64) * 4096;
  const u16* Qh = Qp + (size_t)b * 1048576 + h * 64;
  float* attn = attn_all + (size_t)bh * 4194304;
  char* KsC = (char*)Ks;
  char* PB = (char*)Plds;                  // buf stride 32768, wave stride 8192, strip 4096
  const int swk = (l16 & 7) << 4;

  // K staging geometry (producer threads 0..255)
  const int sr_r = tid >> 3;
  const int sr_c = tid & 7;
  const size_t sr_src = (size_t)sr_r * 1024 + sr_c * 16;
  const int sr_dst = sr_r * 128 + (((sr_c ^ (sr_r & 7))) << 4);
  uint4 sr[4];

#define STAGE_LOAD(KT)                                                         \
  { _Pragma("unroll") for (int jj = 0; jj < 4; ++jj)                           \
      sr[jj] = *(const uint4*)(KhB + (size_t)(KT) * 131072 + (size_t)jj * 32768 + sr_src); }
#define STAGE_WRITE()                                                          \
  { _Pragma("unroll") for (int jj = 0; jj < 4; ++jj)                           \
      *(uint4*)(KsC + jj * 4096 + sr_dst) = sr[jj]; }
#define BARRIER()                                                              \
  { __builtin_amdgcn_s_barrier(); __builtin_amdgcn_sched_barrier(0); }
#define LGKM0()                                                                \
  { asm volatile("s_waitcnt lgkmcnt(0)" ::: "memory");                         \
    __builtin_amdgcn_sched_barrier(0); }

  const int qrH = sHi * 64 + pw * 16;
  const int qrL = sLo * 64 + pw * 16;

  // producer state
  bf16x8 qH0, qH1, qL0, qL1;
  float invH = 0.f, invL = 0.f;
  f32x4 oaccH[4] = {}, oaccL[4] = {};

  if (producer) {
    const int qrowH = qrH + l16, qrowL = qrL + l16;
    qH0 = *(const bf16x8*)(Qh + (size_t)qrowH * 512 + g * 8);
    qH1 = *(const bf16x8*)(Qh + (size_t)qrowH * 512 + 32 + g * 8);
    qL0 = *(const bf16x8*)(Qh + (size_t)qrowL * 512 + g * 8);
    qL1 = *(const bf16x8*)(Qh + (size_t)qrowL * 512 + 32 + g * 8);
    invH = invl[(size_t)bh * 2048 + qrowH];
    invL = invl[(size_t)bh * 2048 + qrowL];
    STAGE_LOAD(0); STAGE_WRITE();
    if (nktH > 1) STAGE_LOAD(1);
    LGKM0();
  }
  BARRIER();

  int cur = 0;
  for (int kt = 0; kt < nktH; ++kt) {
    const int ktb = kt * 128;
    const bool doL = (kt < nktL);
    if (producer) {
      const int qrowH = qrH + l16, qrowL = qrL + l16;
      const bool dH = (kt == nktH - 1), dL = (kt == nktL - 1);
      char* PwH = PB + cur * 32768 + pw * 8192;
      char* PwL = PwH + 4096;
#pragma unroll
      for (int kf = 0; kf < 8; ++kf) {
        const int ro = (kf * 16 + l16) * 128;
        bf16x8 ka = *(const bf16x8*)(KsC + ro + ((g ^ (l16 & 7)) << 4));
        bf16x8 kb = *(const bf16x8*)(KsC + ro + (((4 + g) ^ (l16 & 7)) << 4));
        const int kbase = ktb + kf * 16 + g * 4;
        f32x4 cH = {0.f, 0.f, 0.f, 0.f};
        __builtin_amdgcn_s_setprio(1);
        cH = MFMA_B16(ka, qH0, cH);
        cH = MFMA_B16(kb, qH1, cH);
        __builtin_amdgcn_s_setprio(0);
        {
          float p[4];
#pragma unroll
          for (int r = 0; r < 4; ++r) {
            float e = __expf(cH[r] * 0.125f) * invH;
            p[r] = (dH && (kbase + r > qrowH)) ? 0.f : e;
          }
          unsigned lo = (unsigned)f2bf(p[0]) | ((unsigned)f2bf(p[1]) << 16);
          unsigned hi = (unsigned)f2bf(p[2]) | ((unsigned)f2bf(p[3]) << 16);
          *(uint2*)(PwH + l16 * 256 + ((kf * 32 + g * 8) ^ swk)) = make_uint2(lo, hi);
        }
        if (doL) {
          f32x4 cL = {0.f, 0.f, 0.f, 0.f};
          __builtin_amdgcn_s_setprio(1);
          cL = MFMA_B16(ka, qL0, cL);
          cL = MFMA_B16(kb, qL1, cL);
          __builtin_amdgcn_s_setprio(0);
          float p[4];
#pragma unroll
          for (int r = 0; r < 4; ++r) {
            float e = __expf(cL[r] * 0.125f) * invL;
            p[r] = (dL && (kbase + r > qrowL)) ? 0.f : e;
          }
          unsigned lo = (unsigned)f2bf(p[0]) | ((unsigned)f2bf(p[1]) << 16);
          unsigned hi = (unsigned)f2bf(p[2]) | ((unsigned)f2bf(p[3]) << 16);
          *(uint2*)(PwL + l16 * 256 + ((kf * 32 + g * 8) ^ swk)) = make_uint2(lo, hi);
        }
      }
    } else {
      // consumer: store P[cur^1] (tile kt-1) as f32 attn rows
      if (kt > 0) {
        const int ktbp = (kt - 1) * 128;
        const char* PH = PB + (cur ^ 1) * 32768 + pw * 8192;
        const int c32 = lane & 31;
        const int rh = lane >> 5;
#pragma unroll
        for (int i = 0; i < 8; ++i) {
          const int row = i * 2 + rh;
          uint2 pk = *(const uint2*)(PH + row * 256 + ((c32 * 8) ^ ((row & 7) << 4)));
          f32x4 o;
          o[0] = __uint_as_float(pk.x << 16);
          o[1] = __uint_as_float(pk.x & 0xffff0000u);
          o[2] = __uint_as_float(pk.y << 16);
          o[3] = __uint_as_float(pk.y & 0xffff0000u);
          __builtin_nontemporal_store(o, (f32x4*)(&attn[(size_t)(qrH + row) * 2048 + ktbp + c32 * 4]));
        }
        if (kt - 1 < nktL) {
          const char* PL = PH + 4096;
#pragma unroll
          for (int i = 0; i < 8; ++i) {
            const int row = i * 2 + rh;
            uint2 pk = *(const uint2*)(PL + row * 256 + ((c32 * 8) ^ ((row & 7) << 4)));
            f32x4 o;
            o[0] = __uint_as_float(pk.x << 16);
            o[1] = __uint_as_float(pk.x & 0xffff0000u);
            o[2] = __uint_as_float(pk.y << 16);
            o[3] = __uint_as_float(pk.y & 0xffff0000u);
            __builtin_nontemporal_store(o, (f32x4*)(&attn[(size_t)(qrL + row) * 2048 + ktbp + c32 * 4]));
          }
        }
      }
    }
    LGKM0();
    BARRIER();                           // P[cur] complete; consumer reads done
    if (producer) {
      // restage K for kt+1 (latency hidden under PV), prefetch kt+2
      if (kt + 1 < nktH) {
        STAGE_WRITE();
        if (kt + 2 < nktH) STAGE_LOAD(kt + 2);
      }
      // PV from own P[cur]
      char* PwH = PB + cur * 32768 + pw * 8192;
      char* PwL = PwH + 4096;
#pragma unroll
      for (int kb4 = 0; kb4 < 4; ++kb4) {
        bf16x8 paH = *(const bf16x8*)(PwH + l16 * 256 + ((kb4 * 64 + g * 16) ^ swk));
        bf16x8 paL;
        if (doL) paL = *(const bf16x8*)(PwL + l16 * 256 + ((kb4 * 64 + g * 16) ^ swk));
#pragma unroll
        for (int cn = 0; cn < 4; ++cn) {
          bf16x8 vb = *(const bf16x8*)(VhB + (size_t)(cn * 16 + l16) * 4096 +
                                       (ktb + kb4 * 32 + g * 8) * 2);
          __builtin_amdgcn_s_setprio(1);
          oaccH[cn] = MFMA_B16(paH, vb, oaccH[cn]);
          if (doL) oaccL[cn] = MFMA_B16(paL, vb, oaccL[cn]);
          __builtin_amdgcn_s_setprio(0);
        }
      }
    }
    LGKM0();                             // Ks writes + P reads drained
    BARRIER();
    cur ^= 1;
  }

  if (producer) {
    // ctx writes
    u16* cb = ctx + (size_t)b * 1048576 + h * 64;
#pragma unroll
    for (int cn = 0; cn < 4; ++cn)
#pragma unroll
      for (int r = 0; r < 4; ++r) {
        cb[(size_t)(qrH + g * 4 + r) * 512 + cn * 16 + l16] = f2bf(oaccH[cn][r]);
        cb[(size_t)(qrL + g * 4 + r) * 512 + cn * 16 + l16] = f2bf(oaccL[cn][r]);
      }
  } else {
    // final H tile store (L's last tile was already stored in-loop: nktL < nktH)
    {
      const int ktbp = (nktH - 1) * 128;
      const char* PH = PB + ((nktH - 1) & 1) * 32768 + pw * 8192;
      const int c32 = lane & 31;
      const int rh = lane >> 5;
#pragma unroll
      for (int i = 0; i < 8; ++i) {
        const int row = i * 2 + rh;
        uint2 pk = *(const uint2*)(PH + row * 256 + ((c32 * 8) ^ ((row & 7) << 4)));
        f32x4 o;
        o[0] = __uint_as_float(pk.x << 16);
        o[1] = __uint_as_float(pk.x & 0xffff0000u);
        o[2] = __uint_as_float(pk.y << 16);
        o[3] = __uint_as_float(pk.y & 0xffff0000u);
        __builtin_nontemporal_store(o, (f32x4*)(&attn[(size_t)(qrH + row) * 2048 + ktbp + c32 * 4]));
      }
    }
    // zero-fill strictly-upper tails (consumer waves)
    f32x4 z4 = {0.f, 0.f, 0.f, 0.f};
#pragma unroll
    for (int s2 = 0; s2 < 2; ++s2) {
      const int base = s2 ? sLo * 64 : sHi * 64;
      const int z0 = (s2 ? nktL : nktH) * 128;
      if (z0 < 2048) {
        for (int r = pw; r < 64; r += 4) {
          float* rowp = attn + (size_t)(base + r) * 2048;
          for (int c = z0 + lane * 4; c < 2048; c += 256)
            __builtin_nontemporal_store(z4, (f32x4*)(rowp + c));
        }
      }
    }
  }
#undef STAGE_LOAD
#undef STAGE_WRITE
#undef BARRIER
#undef LGKM0
}

// ---------- residual + LayerNorm ----------
__global__ __launch_bounds__(256) void ln_kernel(const float* __restrict__ proj,
                                                 const float* __restrict__ resid,
                                                 const float* __restrict__ gamma,
                                                 const float* __restrict__ beta,
                                                 float* __restrict__ out) {
  const int wave = threadIdx.x >> 6, lane = threadIdx.x & 63;
  const int row = blockIdx.x * 4 + wave;
  const float4* p4 = (const float4*)(proj + (size_t)row * 512);
  const float4* r4 = (const float4*)(resid + (size_t)row * 512);
  float4 a0 = p4[lane * 2], a1 = p4[lane * 2 + 1];
  float4 q0 = r4[lane * 2], q1 = r4[lane * 2 + 1];
  float x[8];
  x[0] = a0.x + q0.x; x[1] = a0.y + q0.y; x[2] = a0.z + q0.z; x[3] = a0.w + q0.w;
  x[4] = a1.x + q1.x; x[5] = a1.y + q1.y; x[6] = a1.z + q1.z; x[7] = a1.w + q1.w;
  float s = 0.f;
#pragma unroll
  for (int j = 0; j < 8; ++j) s += x[j];
#pragma unroll
  for (int d = 1; d < 64; d <<= 1) s += __shfl_xor(s, d);
  float mu = s * (1.f / 512.f);
  float v = 0.f;
#pragma unroll
  for (int j = 0; j < 8; ++j) { float t = x[j] - mu; v += t * t; }
#pragma unroll
  for (int d = 1; d < 64; d <<= 1) v += __shfl_xor(v, d);
  float rs = rsqrtf(v * (1.f / 512.f) + 1e-5f);
  const float4* g4 = (const float4*)gamma;
  const float4* b4 = (const float4*)beta;
  float4 g0 = g4[lane * 2], g1 = g4[lane * 2 + 1];
  float4 bb0 = b4[lane * 2], bb1 = b4[lane * 2 + 1];
  float4 y0, y1;
  y0.x = (x[0] - mu) * rs * g0.x + bb0.x;
  y0.y = (x[1] - mu) * rs * g0.y + bb0.y;
  y0.z = (x[2] - mu) * rs * g0.z + bb0.z;
  y0.w = (x[3] - mu) * rs * g0.w + bb0.w;
  y1.x = (x[4] - mu) * rs * g1.x + bb1.x;
  y1.y = (x[5] - mu) * rs * g1.y + bb1.y;
  y1.z = (x[6] - mu) * rs * g1.z + bb1.z;
  y1.w = (x[7] - mu) * rs * g1.w + bb1.w;
  float4* o4 = (float4*)(out + (size_t)row * 512);
  o4[lane * 2] = y0;
  o4[lane * 2 + 1] = y1;
}

// ---------- launch ----------
extern "C" void kernel_launch(void* const* d_in, const int* in_sizes, int n_in,
                              void* d_out, int out_size, void* d_ws, size_t ws_size,
                              hipStream_t stream) {
  (void)in_sizes; (void)n_in; (void)out_size; (void)ws_size;
  const float* inQ = (const float*)d_in[0];
  const float* inK = (const float*)d_in[1];
  const float* inV = (const float*)d_in[2];
  const float* Wq = (const float*)d_in[4];
  const float* Wk = (const float*)d_in[5];
  const float* Wv = (const float*)d_in[6];
  const float* Wo = (const float*)d_in[7];
  const float* gamma = (const float*)d_in[8];
  const float* beta = (const float*)d_in[9];

  float* out = (float*)d_out;
  float* attn = out + (size_t)4 * 2048 * 512;

  char* ws = (char*)d_ws;
  u16* Qp  = (u16*)(ws + 0);
  u16* Kp  = (u16*)(ws + 8388608);
  u16* Vp  = (u16*)(ws + 16777216);      // freed after transpose_v -> reused for invl
  u16* Vt  = (u16*)(ws + 25165824);
  u16* ctx = (u16*)(ws + 33554432);
  u16* Wbf = (u16*)(ws + 41943040);
  float* invl = (float*)(ws + 16777216); // 256 KB, overlaps dead Vp
  float* proj = (float*)(ws + 0);        // reuses Qp+Kp after attention
  u16* Xbf = (u16*)attn;

  cvt3<<<2048, 256, 0, stream>>>(inQ, inK, inV, Xbf, 1048576, 4194304);
  cvtW<<<256, 256, 0, stream>>>(Wq, Wk, Wv, Wo, Wbf, 65536, 262144);
  gemm_qkv<<<dim3(64, 4, 3), 256, 0, stream>>>(Xbf, Wbf, Qp);
  transpose_v<<<dim3(32, 8, 4), 256, 0, stream>>>(Vp, Vt);
  lsum_kernel<<<1024, 256, 0, stream>>>(Qp, Kp, invl);
  attn_kernel<<<dim3(512), 512, 0, stream>>>(Qp, Kp, Vt, invl, attn, ctx);
  gemm_f32out<<<dim3(64, 4, 1), 256, 0, stream>>>(ctx, Wbf + (size_t)3 * 262144, proj);
  ln_kernel<<<2048, 256, 0, stream>>>(proj, inQ, gamma, beta, out);
}

// Round 11
// 296.667 us; speedup vs baseline: 1.2065x; 1.1433x over previous
//
#include <hip/hip_runtime.h>

typedef unsigned short u16;
typedef __bf16 bf16x8 __attribute__((ext_vector_type(8)));
typedef float f32x4 __attribute__((ext_vector_type(4)));
typedef unsigned short u16x4 __attribute__((ext_vector_type(4)));

#define MFMA_B16(a, b, c) __builtin_amdgcn_mfma_f32_16x16x32_bf16((a), (b), (c), 0, 0, 0)

// ---------- helpers ----------
__device__ __forceinline__ u16 f2bf(float f) {
  unsigned int u = __float_as_uint(f);
  u += 0x7FFFu + ((u >> 16) & 1u);   // RNE
  return (u16)(u >> 16);
}

__device__ __forceinline__ u16x4 f4_to_bf4(float4 v) {
  u16x4 r;
  r[0] = f2bf(v.x); r[1] = f2bf(v.y); r[2] = f2bf(v.z); r[3] = f2bf(v.w);
  return r;
}

// ---------- f32 -> bf16 converts ----------
__global__ __launch_bounds__(256) void cvt3(const float* __restrict__ a,
                                            const float* __restrict__ b,
                                            const float* __restrict__ c,
                                            u16* __restrict__ dst, int n4, int n) {
  int i = blockIdx.x * 256 + threadIdx.x;
  int stride = gridDim.x * 256;
  const float4* a4 = (const float4*)a;
  const float4* b4 = (const float4*)b;
  const float4* c4 = (const float4*)c;
  u16x4* d0 = (u16x4*)dst;
  u16x4* d1 = (u16x4*)(dst + (size_t)n);
  u16x4* d2 = (u16x4*)(dst + (size_t)2 * n);
  for (; i < n4; i += stride) {
    d0[i] = f4_to_bf4(a4[i]);
    d1[i] = f4_to_bf4(b4[i]);
    d2[i] = f4_to_bf4(c4[i]);
  }
}

__global__ __launch_bounds__(256) void cvtW(const float* __restrict__ a,
                                            const float* __restrict__ b,
                                            const float* __restrict__ c,
                                            const float* __restrict__ d,
                                            u16* __restrict__ dst, int n4, int n) {
  int i = blockIdx.x * 256 + threadIdx.x;
  int stride = gridDim.x * 256;
  const float4* a4 = (const float4*)a;
  const float4* b4 = (const float4*)b;
  const float4* c4 = (const float4*)c;
  const float4* d4 = (const float4*)d;
  u16x4* o0 = (u16x4*)dst;
  u16x4* o1 = (u16x4*)(dst + (size_t)n);
  u16x4* o2 = (u16x4*)(dst + (size_t)2 * n);
  u16x4* o3 = (u16x4*)(dst + (size_t)3 * n);
  for (; i < n4; i += stride) {
    o0[i] = f4_to_bf4(a4[i]);
    o1[i] = f4_to_bf4(b4[i]);
    o2[i] = f4_to_bf4(c4[i]);
    o3[i] = f4_to_bf4(d4[i]);
  }
}

// ---------- B-transposed bf16 GEMM: C[M,512] = A[M,512] * Bw[512,512]^T ----------
template <bool OUT_F32>
__device__ __forceinline__ void gemm_body(const u16* __restrict__ A,
                                          const u16* __restrict__ Bw,
                                          u16* __restrict__ Cb, float* __restrict__ Cf,
                                          int bm, int bn) {
  __shared__ __align__(16) u16 As[128][40];
  __shared__ __align__(16) u16 Bs[128][40];
  const int tid = threadIdx.x;
  const int wave = tid >> 6, lane = tid & 63;
  const int g = lane >> 4, l16 = lane & 15;
  const int wr = (wave >> 1) * 64, wc = (wave & 1) * 64;
  const int srow = tid >> 1, scol = (tid & 1) * 16;
  const u16* Ar = A + (size_t)(bm + srow) * 512 + scol;
  const u16* Br = Bw + (size_t)(bn + srow) * 512 + scol;
  f32x4 acc[4][4] = {};
  for (int k0 = 0; k0 < 512; k0 += 32) {
    *(uint4*)(&As[srow][scol])     = *(const uint4*)(Ar + k0);
    *(uint4*)(&As[srow][scol + 8]) = *(const uint4*)(Ar + k0 + 8);
    *(uint4*)(&Bs[srow][scol])     = *(const uint4*)(Br + k0);
    *(uint4*)(&Bs[srow][scol + 8]) = *(const uint4*)(Br + k0 + 8);
    __syncthreads();
    bf16x8 af[4], bfr[4];
#pragma unroll
    for (int i = 0; i < 4; ++i) af[i] = *(const bf16x8*)(&As[wr + i * 16 + l16][g * 8]);
#pragma unroll
    for (int j = 0; j < 4; ++j) bfr[j] = *(const bf16x8*)(&Bs[wc + j * 16 + l16][g * 8]);
#pragma unroll
    for (int i = 0; i < 4; ++i)
#pragma unroll
      for (int j = 0; j < 4; ++j)
        acc[i][j] = MFMA_B16(af[i], bfr[j], acc[i][j]);
    __syncthreads();
  }
#pragma unroll
  for (int i = 0; i < 4; ++i)
#pragma unroll
    for (int j = 0; j < 4; ++j)
#pragma unroll
      for (int r = 0; r < 4; ++r) {
        int row = bm + wr + i * 16 + g * 4 + r;
        int col = bn + wc + j * 16 + l16;
        if constexpr (OUT_F32)
          Cf[(size_t)row * 512 + col] = acc[i][j][r];
        else
          Cb[(size_t)row * 512 + col] = f2bf(acc[i][j][r]);
      }
}

__global__ __launch_bounds__(256) void gemm_qkv(const u16* __restrict__ Xbf,
                                                const u16* __restrict__ Wbf,
                                                u16* __restrict__ QKVp) {
  int z = blockIdx.z;
  gemm_body<false>(Xbf + (size_t)z * 4194304, Wbf + (size_t)z * 262144,
                   QKVp + (size_t)z * 4194304, nullptr,
                   blockIdx.x * 128, blockIdx.y * 128);
}

__global__ __launch_bounds__(256) void gemm_f32out(const u16* __restrict__ A,
                                                   const u16* __restrict__ Bw,
                                                   float* __restrict__ C) {
  gemm_body<true>(A, Bw, nullptr, C, blockIdx.x * 128, blockIdx.y * 128);
}

// ---------- V transpose: Vp[b][s][d] (bf16) -> Vt[b][d][s] (bf16) ----------
__global__ __launch_bounds__(256) void transpose_v(const u16* __restrict__ Vp,
                                                   u16* __restrict__ Vt) {
  __shared__ __align__(16) u16 t[64][72];
  const int b = blockIdx.z;
  const int s0 = blockIdx.x * 64, d0 = blockIdx.y * 64;
  const u16* in = Vp + (size_t)b * 2048 * 512;
  u16* outp = Vt + (size_t)b * 512 * 2048;
  const int tid = threadIdx.x;
  const int r = tid >> 2;
  const int c = (tid & 3) * 16;
  const uint4* src = (const uint4*)(in + (size_t)(s0 + r) * 512 + d0 + c);
  uint4 v0 = src[0], v1 = src[1];
  *(uint4*)(&t[r][c]) = v0;
  *(uint4*)(&t[r][c + 8]) = v1;
  __syncthreads();
  u16 tmp[16];
#pragma unroll
  for (int j = 0; j < 16; ++j) tmp[j] = t[c + j][r];
  uint4* dst = (uint4*)(outp + (size_t)(d0 + r) * 2048 + s0 + c);
  dst[0] = *(uint4*)(&tmp[0]);
  dst[1] = *(uint4*)(&tmp[8]);
}

// ---------- lsum kernel: invl[bh][q] = 1 / sum_k exp(q.k/8) ----------
__global__ __launch_bounds__(256) void lsum_kernel(const u16* __restrict__ Qp,
                                                   const u16* __restrict__ Kp,
                                                   float* __restrict__ invl) {
  const int wave = threadIdx.x >> 6, lane = threadIdx.x & 63;
  const int g = lane >> 4, l16 = lane & 15;
  const int bx = blockIdx.x;
  const int xcd = bx & 7;
  const int j = bx >> 3;                  // 0..127
  const int bh = xcd * 4 + (j & 3);
  const int qg = 127 - ((j >> 2) * 4 + wave);   // heavy-first
  const int b = bh >> 3, h = bh & 7;
  const u16* Qh = Qp + (size_t)b * 1048576 + h * 64;
  const u16* Kh = Kp + (size_t)b * 1048576 + h * 64;
  const int qrow = qg * 16 + l16;
  bf16x8 q0 = *(const bf16x8*)(Qh + (size_t)qrow * 512 + g * 8);
  bf16x8 q1 = *(const bf16x8*)(Qh + (size_t)qrow * 512 + 32 + g * 8);
  float lsum = 0.f;
  for (int kt = 0; kt < qg; ++kt) {
    const u16* Krow = Kh + (size_t)(kt * 16 + l16) * 512;
    bf16x8 k0 = *(const bf16x8*)(Krow + g * 8);
    bf16x8 k1 = *(const bf16x8*)(Krow + 32 + g * 8);
    f32x4 c = {0.f, 0.f, 0.f, 0.f};
    c = MFMA_B16(k0, q0, c);
    c = MFMA_B16(k1, q1, c);
    lsum += __expf(c[0] * 0.125f) + __expf(c[1] * 0.125f)
          + __expf(c[2] * 0.125f) + __expf(c[3] * 0.125f);
  }
  {  // diagonal chunk
    const u16* Krow = Kh + (size_t)(qg * 16 + l16) * 512;
    bf16x8 k0 = *(const bf16x8*)(Krow + g * 8);
    bf16x8 k1 = *(const bf16x8*)(Krow + 32 + g * 8);
    f32x4 c = {0.f, 0.f, 0.f, 0.f};
    c = MFMA_B16(k0, q0, c);
    c = MFMA_B16(k1, q1, c);
    const int kbase = qg * 16 + g * 4;
#pragma unroll
    for (int r = 0; r < 4; ++r)
      lsum += (kbase + r > qrow) ? 0.f : __expf(c[r] * 0.125f);
  }
  lsum += __shfl_xor(lsum, 16);
  lsum += __shfl_xor(lsum, 32);
  if (lane < 16) invl[(size_t)bh * 2048 + qrow] = 1.f / lsum;
}

// ---------- fused causal attention, v10: R8 schedule at 2x occupancy ----------
// 512 blocks x 512 thr (8 waves). Waves 0-3 own the HEAVY strip (sHi), waves
// 4-7 the LIGHT strip (sLo), 16 q-rows each. K dbuf (2x16KB) staged by all
// 512 threads, schedule identical to R8 (the 301us version). P = 8x4KB.
// LDS 64KB -> 2 blocks/CU = 4 waves/SIMD (was 2). L waves idle-at-barrier
// for kt >= nktL.
__global__ __launch_bounds__(512, 4) void attn_kernel(const u16* __restrict__ Qp,
                                                      const u16* __restrict__ Kp,
                                                      const u16* __restrict__ Vt,
                                                      const float* __restrict__ invl,
                                                      float* __restrict__ attn_all,
                                                      u16* __restrict__ ctx) {
  __shared__ __align__(16) u16 Ks[2][8192];          // 2 x 16KB, chunk-swizzled
  __shared__ __align__(16) u16 Plds[8][16][128];     // 32KB: wave, row, 256B
  const int tid = threadIdx.x;
  const int wave = tid >> 6, lane = tid & 63;
  const int g = lane >> 4, l16 = lane & 15;
  const int strip = wave >> 2;             // 0 = heavy, 1 = light
  const int pw = wave & 3;
  const int id = blockIdx.x;
  const int r8 = id >> 3;
  const int bh = (id & 7) * 4 + (r8 & 3);
  const int pair = r8 >> 2;
  const int sLo = pair, sHi = 31 - pair;
  const int b = bh >> 3, h = bh & 7;
  const int nktH = sHi / 2 + 1, nktL = sLo / 2 + 1;
  const int myNkt = strip ? nktL : nktH;
  const int myS = strip ? sLo : sHi;
  const char* KhB = (const char*)Kp + (size_t)b * 2097152 + h * 128;
  const char* VhB = (const char*)Vt + ((size_t)b * 512 + h * 64) * 4096;
  const u16* Qh = Qp + (size_t)b * 1048576 + h * 64;
  float* attn = attn_all + (size_t)bh * 4194304;
  char* KsC = (char*)Ks;
  char* Pw = (char*)&Plds[wave][0][0];
  const int swk = (l16 & 7) << 4;

  // K staging: 512 threads x 2 chunks of 16B = 16KB tile (128 rows x 128B)
  const int sr_r = tid >> 2;                // row 0..127
  const int sr_c = (tid & 3) * 2;           // chunk 0,2,4,6
  const size_t sr_src = (size_t)sr_r * 1024 + sr_c * 16;
  const int sr_d0 = sr_r * 128 + ((sr_c ^ (sr_r & 7)) << 4);
  const int sr_d1 = sr_r * 128 + (((sr_c + 1) ^ (sr_r & 7)) << 4);
  uint4 sr[2];

#define STAGE_LOAD(KT)                                                         \
  { sr[0] = *(const uint4*)(KhB + (size_t)(KT) * 131072 + sr_src);             \
    sr[1] = *(const uint4*)(KhB + (size_t)(KT) * 131072 + sr_src + 16); }
#define STAGE_WRITE(CUR)                                                       \
  { *(uint4*)(KsC + (CUR) * 16384 + sr_d0) = sr[0];                            \
    *(uint4*)(KsC + (CUR) * 16384 + sr_d1) = sr[1]; }
#define BAR_READS_DONE()                                                       \
  { asm volatile("" ::: "memory");                                             \
    __builtin_amdgcn_s_barrier();                                              \
    __builtin_amdgcn_sched_barrier(0); }
#define BAR_WRITES_VISIBLE()                                                   \
  { asm volatile("s_waitcnt lgkmcnt(0)" ::: "memory");                         \
    __builtin_amdgcn_sched_barrier(0);                                         \
    __builtin_amdgcn_s_barrier();                                              \
    __builtin_amdgcn_sched_barrier(0); }

  const int qr = myS * 64 + pw * 16;
  const int qrow = qr + l16;

  bf16x8 q0 = *(const bf16x8*)(Qh + (size_t)qrow * 512 + g * 8);
  bf16x8 q1 = *(const bf16x8*)(Qh + (size_t)qrow * 512 + 32 + g * 8);
  const float inv = invl[(size_t)bh * 2048 + qrow];

  f32x4 oacc[4] = {};
  {
    STAGE_LOAD(0); STAGE_WRITE(0);
    if (nktH > 1) STAGE_LOAD(1);
    BAR_WRITES_VISIBLE();
    int cur = 0;
    for (int kt = 0; kt < nktH; ++kt) {
      const int ktb = kt * 128;
      const bool act = (kt < myNkt);
      const bool dg = (kt == myNkt - 1);
      const char* Kc = KsC + cur * 16384;
      if (act) {
#pragma unroll
        for (int kf = 0; kf < 8; ++kf) {
          const int ro = (kf * 16 + l16) * 128;
          bf16x8 ka = *(const bf16x8*)(Kc + ro + ((g ^ (l16 & 7)) << 4));
          bf16x8 kb = *(const bf16x8*)(Kc + ro + (((4 + g) ^ (l16 & 7)) << 4));
          const int kbase = ktb + kf * 16 + g * 4;
          f32x4 c = {0.f, 0.f, 0.f, 0.f};
          __builtin_amdgcn_s_setprio(1);
          c = MFMA_B16(ka, q0, c);
          c = MFMA_B16(kb, q1, c);
          __builtin_amdgcn_s_setprio(0);
          float p[4];
#pragma unroll
          for (int r = 0; r < 4; ++r) {
            float e = __expf(c[r] * 0.125f) * inv;
            p[r] = (dg && (kbase + r > qrow)) ? 0.f : e;
          }
          unsigned lo = (unsigned)f2bf(p[0]) | ((unsigned)f2bf(p[1]) << 16);
          unsigned hi = (unsigned)f2bf(p[2]) | ((unsigned)f2bf(p[3]) << 16);
          *(uint2*)(Pw + l16 * 256 + ((kf * 32 + g * 8) ^ swk)) = make_uint2(lo, hi);
        }
        // PV
#pragma unroll
        for (int kb4 = 0; kb4 < 4; ++kb4) {
          bf16x8 pa = *(const bf16x8*)(Pw + l16 * 256 + ((kb4 * 64 + g * 16) ^ swk));
#pragma unroll
          for (int cn = 0; cn < 4; ++cn) {
            bf16x8 vb = *(const bf16x8*)(VhB + (size_t)(cn * 16 + l16) * 4096 +
                                         (ktb + kb4 * 32 + g * 8) * 2);
            __builtin_amdgcn_s_setprio(1);
            oacc[cn] = MFMA_B16(pa, vb, oacc[cn]);
            __builtin_amdgcn_s_setprio(0);
          }
        }
        // attn nt-stores: 2 rows x 512B contiguous per instruction
        {
          const int c32 = lane & 31;
          const int rh = lane >> 5;
#pragma unroll
          for (int i = 0; i < 8; ++i) {
            const int row = i * 2 + rh;
            uint2 pk = *(const uint2*)(Pw + row * 256 + ((c32 * 8) ^ ((row & 7) << 4)));
            f32x4 o;
            o[0] = __uint_as_float(pk.x << 16);
            o[1] = __uint_as_float(pk.x & 0xffff0000u);
            o[2] = __uint_as_float(pk.y << 16);
            o[3] = __uint_as_float(pk.y & 0xffff0000u);
            __builtin_nontemporal_store(o, (f32x4*)(&attn[(size_t)(qr + row) * 2048 + ktb + c32 * 4]));
          }
        }
      }
      if (kt + 1 < nktH) {
        BAR_READS_DONE();                // all waves done reading Ks[cur^1]
        STAGE_WRITE(cur ^ 1);
        if (kt + 2 < nktH) STAGE_LOAD(kt + 2);
        BAR_WRITES_VISIBLE();
        cur ^= 1;
      }
    }
  }

  // ctx write
  u16* cb = ctx + (size_t)b * 1048576 + h * 64;
#pragma unroll
  for (int cn = 0; cn < 4; ++cn)
#pragma unroll
    for (int r = 0; r < 4; ++r)
      cb[(size_t)(qr + g * 4 + r) * 512 + cn * 16 + l16] = f2bf(oacc[cn][r]);

  // zero-fill strictly-upper tail of my strip (4 waves per strip)
  {
    const int base = myS * 64;
    const int z0 = myNkt * 128;
    f32x4 z4 = {0.f, 0.f, 0.f, 0.f};
    if (z0 < 2048) {
      for (int r = pw; r < 64; r += 4) {
        float* rowp = attn + (size_t)(base + r) * 2048;
        for (int c = z0 + lane * 4; c < 2048; c += 256)
          __builtin_nontemporal_store(z4, (f32x4*)(rowp + c));
      }
    }
  }
#undef STAGE_LOAD
#undef STAGE_WRITE
#undef BAR_READS_DONE
#undef BAR_WRITES_VISIBLE
}

// ---------- residual + LayerNorm ----------
__global__ __launch_bounds__(256) void ln_kernel(const float* __restrict__ proj,
                                                 const float* __restrict__ resid,
                                                 const float* __restrict__ gamma,
                                                 const float* __restrict__ beta,
                                                 float* __restrict__ out) {
  const int wave = threadIdx.x >> 6, lane = threadIdx.x & 63;
  const int row = blockIdx.x * 4 + wave;
  const float4* p4 = (const float4*)(proj + (size_t)row * 512);
  const float4* r4 = (const float4*)(resid + (size_t)row * 512);
  float4 a0 = p4[lane * 2], a1 = p4[lane * 2 + 1];
  float4 q0 = r4[lane * 2], q1 = r4[lane * 2 + 1];
  float x[8];
  x[0] = a0.x + q0.x; x[1] = a0.y + q0.y; x[2] = a0.z + q0.z; x[3] = a0.w + q0.w;
  x[4] = a1.x + q1.x; x[5] = a1.y + q1.y; x[6] = a1.z + q1.z; x[7] = a1.w + q1.w;
  float s = 0.f;
#pragma unroll
  for (int j = 0; j < 8; ++j) s += x[j];
#pragma unroll
  for (int d = 1; d < 64; d <<= 1) s += __shfl_xor(s, d);
  float mu = s * (1.f / 512.f);
  float v = 0.f;
#pragma unroll
  for (int j = 0; j < 8; ++j) { float t = x[j] - mu; v += t * t; }
#pragma unroll
  for (int d = 1; d < 64; d <<= 1) v += __shfl_xor(v, d);
  float rs = rsqrtf(v * (1.f / 512.f) + 1e-5f);
  const float4* g4 = (const float4*)gamma;
  const float4* b4 = (const float4*)beta;
  float4 g0 = g4[lane * 2], g1 = g4[lane * 2 + 1];
  float4 bb0 = b4[lane * 2], bb1 = b4[lane * 2 + 1];
  float4 y0, y1;
  y0.x = (x[0] - mu) * rs * g0.x + bb0.x;
  y0.y = (x[1] - mu) * rs * g0.y + bb0.y;
  y0.z = (x[2] - mu) * rs * g0.z + bb0.z;
  y0.w = (x[3] - mu) * rs * g0.w + bb0.w;
  y1.x = (x[4] - mu) * rs * g1.x + bb1.x;
  y1.y = (x[5] - mu) * rs * g1.y + bb1.y;
  y1.z = (x[6] - mu) * rs * g1.z + bb1.z;
  y1.w = (x[7] - mu) * rs * g1.w + bb1.w;
  float4* o4 = (float4*)(out + (size_t)row * 512);
  o4[lane * 2] = y0;
  o4[lane * 2 + 1] = y1;
}

// ---------- launch ----------
extern "C" void kernel_launch(void* const* d_in, const int* in_sizes, int n_in,
                              void* d_out, int out_size, void* d_ws, size_t ws_size,
                              hipStream_t stream) {
  (void)in_sizes; (void)n_in; (void)out_size; (void)ws_size;
  const float* inQ = (const float*)d_in[0];
  const float* inK = (const float*)d_in[1];
  const float* inV = (const float*)d_in[2];
  const float* Wq = (const float*)d_in[4];
  const float* Wk = (const float*)d_in[5];
  const float* Wv = (const float*)d_in[6];
  const float* Wo = (const float*)d_in[7];
  const float* gamma = (const float*)d_in[8];
  const float* beta = (const float*)d_in[9];

  float* out = (float*)d_out;
  float* attn = out + (size_t)4 * 2048 * 512;

  char* ws = (char*)d_ws;
  u16* Qp  = (u16*)(ws + 0);
  u16* Kp  = (u16*)(ws + 8388608);
  u16* Vp  = (u16*)(ws + 16777216);      // freed after transpose_v -> reused for invl
  u16* Vt  = (u16*)(ws + 25165824);
  u16* ctx = (u16*)(ws + 33554432);
  u16* Wbf = (u16*)(ws + 41943040);
  float* invl = (float*)(ws + 16777216); // 256 KB, overlaps dead Vp
  float* proj = (float*)(ws + 0);        // reuses Qp+Kp after attention
  u16* Xbf = (u16*)attn;

  cvt3<<<2048, 256, 0, stream>>>(inQ, inK, inV, Xbf, 1048576, 4194304);
  cvtW<<<256, 256, 0, stream>>>(Wq, Wk, Wv, Wo, Wbf, 65536, 262144);
  gemm_qkv<<<dim3(64, 4, 3), 256, 0, stream>>>(Xbf, Wbf, Qp);
  transpose_v<<<dim3(32, 8, 4), 256, 0, stream>>>(Vp, Vt);
  lsum_kernel<<<1024, 256, 0, stream>>>(Qp, Kp, invl);
  attn_kernel<<<dim3(512), 512, 0, stream>>>(Qp, Kp, Vt, invl, attn, ctx);
  gemm_f32out<<<dim3(64, 4, 1), 256, 0, stream>>>(ctx, Wbf + (size_t)3 * 262144, proj);
  ln_kernel<<<2048, 256, 0, stream>>>(proj, inQ, gamma, beta, out);
}

// Round 12
// 267.986 us; speedup vs baseline: 1.3357x; 1.1070x over previous
//
#include <hip/hip_runtime.h>

typedef unsigned short u16;
typedef __bf16 bf16x8 __attribute__((ext_vector_type(8)));
typedef float f32x4 __attribute__((ext_vector_type(4)));
typedef unsigned short u16x4 __attribute__((ext_vector_type(4)));

#define MFMA_B16(a, b, c) __builtin_amdgcn_mfma_f32_16x16x32_bf16((a), (b), (c), 0, 0, 0)

// ---------- helpers ----------
__device__ __forceinline__ u16 f2bf(float f) {
  unsigned int u = __float_as_uint(f);
  u += 0x7FFFu + ((u >> 16) & 1u);   // RNE
  return (u16)(u >> 16);
}

__device__ __forceinline__ u16x4 f4_to_bf4(float4 v) {
  u16x4 r;
  r[0] = f2bf(v.x); r[1] = f2bf(v.y); r[2] = f2bf(v.z); r[3] = f2bf(v.w);
  return r;
}

// ---------- f32 -> bf16 converts ----------
__global__ __launch_bounds__(256) void cvt3(const float* __restrict__ a,
                                            const float* __restrict__ b,
                                            const float* __restrict__ c,
                                            u16* __restrict__ dst, int n4, int n) {
  int i = blockIdx.x * 256 + threadIdx.x;
  int stride = gridDim.x * 256;
  const float4* a4 = (const float4*)a;
  const float4* b4 = (const float4*)b;
  const float4* c4 = (const float4*)c;
  u16x4* d0 = (u16x4*)dst;
  u16x4* d1 = (u16x4*)(dst + (size_t)n);
  u16x4* d2 = (u16x4*)(dst + (size_t)2 * n);
  for (; i < n4; i += stride) {
    d0[i] = f4_to_bf4(a4[i]);
    d1[i] = f4_to_bf4(b4[i]);
    d2[i] = f4_to_bf4(c4[i]);
  }
}

__global__ __launch_bounds__(256) void cvtW(const float* __restrict__ a,
                                            const float* __restrict__ b,
                                            const float* __restrict__ c,
                                            const float* __restrict__ d,
                                            u16* __restrict__ dst, int n4, int n) {
  int i = blockIdx.x * 256 + threadIdx.x;
  int stride = gridDim.x * 256;
  const float4* a4 = (const float4*)a;
  const float4* b4 = (const float4*)b;
  const float4* c4 = (const float4*)c;
  const float4* d4 = (const float4*)d;
  u16x4* o0 = (u16x4*)dst;
  u16x4* o1 = (u16x4*)(dst + (size_t)n);
  u16x4* o2 = (u16x4*)(dst + (size_t)2 * n);
  u16x4* o3 = (u16x4*)(dst + (size_t)3 * n);
  for (; i < n4; i += stride) {
    o0[i] = f4_to_bf4(a4[i]);
    o1[i] = f4_to_bf4(b4[i]);
    o2[i] = f4_to_bf4(c4[i]);
    o3[i] = f4_to_bf4(d4[i]);
  }
}

// ---------- B-transposed bf16 GEMM: C[M,512] = A[M,512] * Bw[512,512]^T ----------
template <bool OUT_F32>
__device__ __forceinline__ void gemm_body(const u16* __restrict__ A,
                                          const u16* __restrict__ Bw,
                                          u16* __restrict__ Cb, float* __restrict__ Cf,
                                          int bm, int bn) {
  __shared__ __align__(16) u16 As[128][40];
  __shared__ __align__(16) u16 Bs[128][40];
  const int tid = threadIdx.x;
  const int wave = tid >> 6, lane = tid & 63;
  const int g = lane >> 4, l16 = lane & 15;
  const int wr = (wave >> 1) * 64, wc = (wave & 1) * 64;
  const int srow = tid >> 1, scol = (tid & 1) * 16;
  const u16* Ar = A + (size_t)(bm + srow) * 512 + scol;
  const u16* Br = Bw + (size_t)(bn + srow) * 512 + scol;
  f32x4 acc[4][4] = {};
  for (int k0 = 0; k0 < 512; k0 += 32) {
    *(uint4*)(&As[srow][scol])     = *(const uint4*)(Ar + k0);
    *(uint4*)(&As[srow][scol + 8]) = *(const uint4*)(Ar + k0 + 8);
    *(uint4*)(&Bs[srow][scol])     = *(const uint4*)(Br + k0);
    *(uint4*)(&Bs[srow][scol + 8]) = *(const uint4*)(Br + k0 + 8);
    __syncthreads();
    bf16x8 af[4], bfr[4];
#pragma unroll
    for (int i = 0; i < 4; ++i) af[i] = *(const bf16x8*)(&As[wr + i * 16 + l16][g * 8]);
#pragma unroll
    for (int j = 0; j < 4; ++j) bfr[j] = *(const bf16x8*)(&Bs[wc + j * 16 + l16][g * 8]);
#pragma unroll
    for (int i = 0; i < 4; ++i)
#pragma unroll
      for (int j = 0; j < 4; ++j)
        acc[i][j] = MFMA_B16(af[i], bfr[j], acc[i][j]);
    __syncthreads();
  }
#pragma unroll
  for (int i = 0; i < 4; ++i)
#pragma unroll
    for (int j = 0; j < 4; ++j)
#pragma unroll
      for (int r = 0; r < 4; ++r) {
        int row = bm + wr + i * 16 + g * 4 + r;
        int col = bn + wc + j * 16 + l16;
        if constexpr (OUT_F32)
          Cf[(size_t)row * 512 + col] = acc[i][j][r];
        else
          Cb[(size_t)row * 512 + col] = f2bf(acc[i][j][r]);
      }
}

__global__ __launch_bounds__(256) void gemm_qkv(const u16* __restrict__ Xbf,
                                                const u16* __restrict__ Wbf,
                                                u16* __restrict__ QKVp) {
  int z = blockIdx.z;
  gemm_body<false>(Xbf + (size_t)z * 4194304, Wbf + (size_t)z * 262144,
                   QKVp + (size_t)z * 4194304, nullptr,
                   blockIdx.x * 128, blockIdx.y * 128);
}

__global__ __launch_bounds__(256) void gemm_f32out(const u16* __restrict__ A,
                                                   const u16* __restrict__ Bw,
                                                   float* __restrict__ C) {
  gemm_body<true>(A, Bw, nullptr, C, blockIdx.x * 128, blockIdx.y * 128);
}

// ---------- V transpose: Vp[b][s][d] (bf16) -> Vt[b][d][s] (bf16) ----------
__global__ __launch_bounds__(256) void transpose_v(const u16* __restrict__ Vp,
                                                   u16* __restrict__ Vt) {
  __shared__ __align__(16) u16 t[64][72];
  const int b = blockIdx.z;
  const int s0 = blockIdx.x * 64, d0 = blockIdx.y * 64;
  const u16* in = Vp + (size_t)b * 2048 * 512;
  u16* outp = Vt + (size_t)b * 512 * 2048;
  const int tid = threadIdx.x;
  const int r = tid >> 2;
  const int c = (tid & 3) * 16;
  const uint4* src = (const uint4*)(in + (size_t)(s0 + r) * 512 + d0 + c);
  uint4 v0 = src[0], v1 = src[1];
  *(uint4*)(&t[r][c]) = v0;
  *(uint4*)(&t[r][c + 8]) = v1;
  __syncthreads();
  u16 tmp[16];
#pragma unroll
  for (int j = 0; j < 16; ++j) tmp[j] = t[c + j][r];
  uint4* dst = (uint4*)(outp + (size_t)(d0 + r) * 2048 + s0 + c);
  dst[0] = *(uint4*)(&tmp[0]);
  dst[1] = *(uint4*)(&tmp[8]);
}

// ---------- lsum v2: K-tile LDS sharing ----------
// 256 blocks x 512 thr. Block = (bh XCD-pinned, row-pair {p, 15-p} of 128
// q-rows each). Waves 0-3: heavy strip (15-p), waves 4-7: light strip (p),
// 32 q-rows per wave. K tile (128x64 bf16 = 16KB) double-buffered in LDS,
// staged once per block, shared by all 8 waves & both strips (light's kt
// range is a prefix of heavy's). Uniform 17 tile-iters/block on 256 CUs.
// K L2 traffic: 4.2 GB (old per-wave streaming) -> ~70 MB.
__global__ __launch_bounds__(512, 2) void lsum_kernel(const u16* __restrict__ Qp,
                                                      const u16* __restrict__ Kp,
                                                      float* __restrict__ invl) {
  __shared__ __align__(16) u16 Ks[2][8192];          // 2 x 16KB, chunk-swizzled
  const int tid = threadIdx.x;
  const int wave = tid >> 6, lane = tid & 63;
  const int g = lane >> 4, l16 = lane & 15;
  const int id = blockIdx.x;
  const int xcd = id & 7;
  const int r = id >> 3;                  // 0..31
  const int bh = xcd * 4 + (r & 3);       // all blocks of bh on one XCD
  const int p = r >> 2;                   // 0..7
  const int strip = wave >> 2;            // 0 = heavy, 1 = light
  const int pw = wave & 3;
  const int nktH = 16 - p, nktL = p + 1;
  const int myNkt = strip ? nktL : nktH;
  const int myBase = (strip ? p : 15 - p) * 128 + pw * 32;
  const int b = bh >> 3, h = bh & 7;
  const char* KhB = (const char*)Kp + (size_t)b * 2097152 + h * 128;  // K row = 1024B
  const u16* Qh = Qp + (size_t)b * 1048576 + h * 64;
  char* KsC = (char*)Ks;

  // staging: 512 threads x 2 chunks of 16B = 16KB tile (128 rows x 128B)
  const int sr_r = tid >> 2;
  const int sr_c = (tid & 3) * 2;
  const size_t sr_src = (size_t)sr_r * 1024 + sr_c * 16;
  const int sr_d0 = sr_r * 128 + ((sr_c ^ (sr_r & 7)) << 4);
  const int sr_d1 = sr_r * 128 + (((sr_c + 1) ^ (sr_r & 7)) << 4);
  uint4 sr[2];

#define STAGE_LOAD(KT)                                                         \
  { sr[0] = *(const uint4*)(KhB + (size_t)(KT) * 131072 + sr_src);             \
    sr[1] = *(const uint4*)(KhB + (size_t)(KT) * 131072 + sr_src + 16); }
#define STAGE_WRITE(CUR)                                                       \
  { *(uint4*)(KsC + (CUR) * 16384 + sr_d0) = sr[0];                            \
    *(uint4*)(KsC + (CUR) * 16384 + sr_d1) = sr[1]; }
#define BAR_READS_DONE()                                                       \
  { asm volatile("" ::: "memory");                                             \
    __builtin_amdgcn_s_barrier();                                              \
    __builtin_amdgcn_sched_barrier(0); }
#define BAR_WRITES_VISIBLE()                                                   \
  { asm volatile("s_waitcnt lgkmcnt(0)" ::: "memory");                         \
    __builtin_amdgcn_sched_barrier(0);                                         \
    __builtin_amdgcn_s_barrier();                                              \
    __builtin_amdgcn_sched_barrier(0); }

  const int qrow0 = myBase + l16;
  const int qrow1 = myBase + 16 + l16;
  bf16x8 q00 = *(const bf16x8*)(Qh + (size_t)qrow0 * 512 + g * 8);
  bf16x8 q01 = *(const bf16x8*)(Qh + (size_t)qrow0 * 512 + 32 + g * 8);
  bf16x8 q10 = *(const bf16x8*)(Qh + (size_t)qrow1 * 512 + g * 8);
  bf16x8 q11 = *(const bf16x8*)(Qh + (size_t)qrow1 * 512 + 32 + g * 8);

  float ls0 = 0.f, ls1 = 0.f;
  STAGE_LOAD(0); STAGE_WRITE(0);
  if (nktH > 1) STAGE_LOAD(1);
  BAR_WRITES_VISIBLE();
  int cur = 0;
  for (int kt = 0; kt < nktH; ++kt) {
    const int ktb = kt * 128;
    const bool act = (kt < myNkt);
    const bool dg = (kt == myNkt - 1);
    const char* Kc = KsC + cur * 16384;
    if (act) {
#pragma unroll
      for (int kf = 0; kf < 8; ++kf) {
        const int ro = (kf * 16 + l16) * 128;
        bf16x8 ka = *(const bf16x8*)(Kc + ro + ((g ^ (l16 & 7)) << 4));
        bf16x8 kb = *(const bf16x8*)(Kc + ro + (((4 + g) ^ (l16 & 7)) << 4));
        const int kbase = ktb + kf * 16 + g * 4;
        f32x4 c0 = {0.f, 0.f, 0.f, 0.f};
        f32x4 c1 = {0.f, 0.f, 0.f, 0.f};
        __builtin_amdgcn_s_setprio(1);
        c0 = MFMA_B16(ka, q00, c0);
        c0 = MFMA_B16(kb, q01, c0);
        c1 = MFMA_B16(ka, q10, c1);
        c1 = MFMA_B16(kb, q11, c1);
        __builtin_amdgcn_s_setprio(0);
        if (dg) {
#pragma unroll
          for (int rr = 0; rr < 4; ++rr) {
            ls0 += (kbase + rr > qrow0) ? 0.f : __expf(c0[rr] * 0.125f);
            ls1 += (kbase + rr > qrow1) ? 0.f : __expf(c1[rr] * 0.125f);
          }
        } else {
          ls0 += __expf(c0[0] * 0.125f) + __expf(c0[1] * 0.125f)
               + __expf(c0[2] * 0.125f) + __expf(c0[3] * 0.125f);
          ls1 += __expf(c1[0] * 0.125f) + __expf(c1[1] * 0.125f)
               + __expf(c1[2] * 0.125f) + __expf(c1[3] * 0.125f);
        }
      }
    }
    if (kt + 1 < nktH) {
      BAR_READS_DONE();
      STAGE_WRITE(cur ^ 1);
      if (kt + 2 < nktH) STAGE_LOAD(kt + 2);
      BAR_WRITES_VISIBLE();
      cur ^= 1;
    }
  }
  ls0 += __shfl_xor(ls0, 16); ls0 += __shfl_xor(ls0, 32);
  ls1 += __shfl_xor(ls1, 16); ls1 += __shfl_xor(ls1, 32);
  if (lane < 16) {
    invl[(size_t)bh * 2048 + qrow0] = 1.f / ls0;
    invl[(size_t)bh * 2048 + qrow1] = 1.f / ls1;
  }
#undef STAGE_LOAD
#undef STAGE_WRITE
#undef BAR_READS_DONE
#undef BAR_WRITES_VISIBLE
}

// ---------- fused causal attention, v10: R8 schedule at 2x occupancy ----------
// 512 blocks x 512 thr (8 waves). Waves 0-3 own the HEAVY strip (sHi), waves
// 4-7 the LIGHT strip (sLo), 16 q-rows each. K dbuf (2x16KB) staged by all
// 512 threads. P = 8x4KB. LDS 64KB -> 2 blocks/CU = 4 waves/SIMD.
__global__ __launch_bounds__(512, 4) void attn_kernel(const u16* __restrict__ Qp,
                                                      const u16* __restrict__ Kp,
                                                      const u16* __restrict__ Vt,
                                                      const float* __restrict__ invl,
                                                      float* __restrict__ attn_all,
                                                      u16* __restrict__ ctx) {
  __shared__ __align__(16) u16 Ks[2][8192];          // 2 x 16KB, chunk-swizzled
  __shared__ __align__(16) u16 Plds[8][16][128];     // 32KB: wave, row, 256B
  const int tid = threadIdx.x;
  const int wave = tid >> 6, lane = tid & 63;
  const int g = lane >> 4, l16 = lane & 15;
  const int strip = wave >> 2;             // 0 = heavy, 1 = light
  const int pw = wave & 3;
  const int id = blockIdx.x;
  const int r8 = id >> 3;
  const int bh = (id & 7) * 4 + (r8 & 3);
  const int pair = r8 >> 2;
  const int sLo = pair, sHi = 31 - pair;
  const int b = bh >> 3, h = bh & 7;
  const int nktH = sHi / 2 + 1, nktL = sLo / 2 + 1;
  const int myNkt = strip ? nktL : nktH;
  const int myS = strip ? sLo : sHi;
  const char* KhB = (const char*)Kp + (size_t)b * 2097152 + h * 128;
  const char* VhB = (const char*)Vt + ((size_t)b * 512 + h * 64) * 4096;
  const u16* Qh = Qp + (size_t)b * 1048576 + h * 64;
  float* attn = attn_all + (size_t)bh * 4194304;
  char* KsC = (char*)Ks;
  char* Pw = (char*)&Plds[wave][0][0];
  const int swk = (l16 & 7) << 4;

  const int sr_r = tid >> 2;                // row 0..127
  const int sr_c = (tid & 3) * 2;           // chunk 0,2,4,6
  const size_t sr_src = (size_t)sr_r * 1024 + sr_c * 16;
  const int sr_d0 = sr_r * 128 + ((sr_c ^ (sr_r & 7)) << 4);
  const int sr_d1 = sr_r * 128 + (((sr_c + 1) ^ (sr_r & 7)) << 4);
  uint4 sr[2];

#define STAGE_LOAD(KT)                                                         \
  { sr[0] = *(const uint4*)(KhB + (size_t)(KT) * 131072 + sr_src);             \
    sr[1] = *(const uint4*)(KhB + (size_t)(KT) * 131072 + sr_src + 16); }
#define STAGE_WRITE(CUR)                                                       \
  { *(uint4*)(KsC + (CUR) * 16384 + sr_d0) = sr[0];                            \
    *(uint4*)(KsC + (CUR) * 16384 + sr_d1) = sr[1]; }
#define BAR_READS_DONE()                                                       \
  { asm volatile("" ::: "memory");                                             \
    __builtin_amdgcn_s_barrier();                                              \
    __builtin_amdgcn_sched_barrier(0); }
#define BAR_WRITES_VISIBLE()                                                   \
  { asm volatile("s_waitcnt lgkmcnt(0)" ::: "memory");                         \
    __builtin_amdgcn_sched_barrier(0);                                         \
    __builtin_amdgcn_s_barrier();                                              \
    __builtin_amdgcn_sched_barrier(0); }

  const int qr = myS * 64 + pw * 16;
  const int qrow = qr + l16;

  bf16x8 q0 = *(const bf16x8*)(Qh + (size_t)qrow * 512 + g * 8);
  bf16x8 q1 = *(const bf16x8*)(Qh + (size_t)qrow * 512 + 32 + g * 8);
  const float inv = invl[(size_t)bh * 2048 + qrow];

  f32x4 oacc[4] = {};
  {
    STAGE_LOAD(0); STAGE_WRITE(0);
    if (nktH > 1) STAGE_LOAD(1);
    BAR_WRITES_VISIBLE();
    int cur = 0;
    for (int kt = 0; kt < nktH; ++kt) {
      const int ktb = kt * 128;
      const bool act = (kt < myNkt);
      const bool dg = (kt == myNkt - 1);
      const char* Kc = KsC + cur * 16384;
      if (act) {
#pragma unroll
        for (int kf = 0; kf < 8; ++kf) {
          const int ro = (kf * 16 + l16) * 128;
          bf16x8 ka = *(const bf16x8*)(Kc + ro + ((g ^ (l16 & 7)) << 4));
          bf16x8 kb = *(const bf16x8*)(Kc + ro + (((4 + g) ^ (l16 & 7)) << 4));
          const int kbase = ktb + kf * 16 + g * 4;
          f32x4 c = {0.f, 0.f, 0.f, 0.f};
          __builtin_amdgcn_s_setprio(1);
          c = MFMA_B16(ka, q0, c);
          c = MFMA_B16(kb, q1, c);
          __builtin_amdgcn_s_setprio(0);
          float p[4];
#pragma unroll
          for (int r = 0; r < 4; ++r) {
            float e = __expf(c[r] * 0.125f) * inv;
            p[r] = (dg && (kbase + r > qrow)) ? 0.f : e;
          }
          unsigned lo = (unsigned)f2bf(p[0]) | ((unsigned)f2bf(p[1]) << 16);
          unsigned hi = (unsigned)f2bf(p[2]) | ((unsigned)f2bf(p[3]) << 16);
          *(uint2*)(Pw + l16 * 256 + ((kf * 32 + g * 8) ^ swk)) = make_uint2(lo, hi);
        }
        // PV
#pragma unroll
        for (int kb4 = 0; kb4 < 4; ++kb4) {
          bf16x8 pa = *(const bf16x8*)(Pw + l16 * 256 + ((kb4 * 64 + g * 16) ^ swk));
#pragma unroll
          for (int cn = 0; cn < 4; ++cn) {
            bf16x8 vb = *(const bf16x8*)(VhB + (size_t)(cn * 16 + l16) * 4096 +
                                         (ktb + kb4 * 32 + g * 8) * 2);
            __builtin_amdgcn_s_setprio(1);
            oacc[cn] = MFMA_B16(pa, vb, oacc[cn]);
            __builtin_amdgcn_s_setprio(0);
          }
        }
        // attn nt-stores: 2 rows x 512B contiguous per instruction
        {
          const int c32 = lane & 31;
          const int rh = lane >> 5;
#pragma unroll
          for (int i = 0; i < 8; ++i) {
            const int row = i * 2 + rh;
            uint2 pk = *(const uint2*)(Pw + row * 256 + ((c32 * 8) ^ ((row & 7) << 4)));
            f32x4 o;
            o[0] = __uint_as_float(pk.x << 16);
            o[1] = __uint_as_float(pk.x & 0xffff0000u);
            o[2] = __uint_as_float(pk.y << 16);
            o[3] = __uint_as_float(pk.y & 0xffff0000u);
            __builtin_nontemporal_store(o, (f32x4*)(&attn[(size_t)(qr + row) * 2048 + ktb + c32 * 4]));
          }
        }
      }
      if (kt + 1 < nktH) {
        BAR_READS_DONE();
        STAGE_WRITE(cur ^ 1);
        if (kt + 2 < nktH) STAGE_LOAD(kt + 2);
        BAR_WRITES_VISIBLE();
        cur ^= 1;
      }
    }
  }

  // ctx write
  u16* cb = ctx + (size_t)b * 1048576 + h * 64;
#pragma unroll
  for (int cn = 0; cn < 4; ++cn)
#pragma unroll
    for (int r = 0; r < 4; ++r)
      cb[(size_t)(qr + g * 4 + r) * 512 + cn * 16 + l16] = f2bf(oacc[cn][r]);

  // zero-fill strictly-upper tail of my strip (4 waves per strip)
  {
    const int base = myS * 64;
    const int z0 = myNkt * 128;
    f32x4 z4 = {0.f, 0.f, 0.f, 0.f};
    if (z0 < 2048) {
      for (int r = pw; r < 64; r += 4) {
        float* rowp = attn + (size_t)(base + r) * 2048;
        for (int c = z0 + lane * 4; c < 2048; c += 256)
          __builtin_nontemporal_store(z4, (f32x4*)(rowp + c));
      }
    }
  }
#undef STAGE_LOAD
#undef STAGE_WRITE
#undef BAR_READS_DONE
#undef BAR_WRITES_VISIBLE
}

// ---------- residual + LayerNorm ----------
__global__ __launch_bounds__(256) void ln_kernel(const float* __restrict__ proj,
                                                 const float* __restrict__ resid,
                                                 const float* __restrict__ gamma,
                                                 const float* __restrict__ beta,
                                                 float* __restrict__ out) {
  const int wave = threadIdx.x >> 6, lane = threadIdx.x & 63;
  const int row = blockIdx.x * 4 + wave;
  const float4* p4 = (const float4*)(proj + (size_t)row * 512);
  const float4* r4 = (const float4*)(resid + (size_t)row * 512);
  float4 a0 = p4[lane * 2], a1 = p4[lane * 2 + 1];
  float4 q0 = r4[lane * 2], q1 = r4[lane * 2 + 1];
  float x[8];
  x[0] = a0.x + q0.x; x[1] = a0.y + q0.y; x[2] = a0.z + q0.z; x[3] = a0.w + q0.w;
  x[4] = a1.x + q1.x; x[5] = a1.y + q1.y; x[6] = a1.z + q1.z; x[7] = a1.w + q1.w;
  float s = 0.f;
#pragma unroll
  for (int j = 0; j < 8; ++j) s += x[j];
#pragma unroll
  for (int d = 1; d < 64; d <<= 1) s += __shfl_xor(s, d);
  float mu = s * (1.f / 512.f);
  float v = 0.f;
#pragma unroll
  for (int j = 0; j < 8; ++j) { float t = x[j] - mu; v += t * t; }
#pragma unroll
  for (int d = 1; d < 64; d <<= 1) v += __shfl_xor(v, d);
  float rs = rsqrtf(v * (1.f / 512.f) + 1e-5f);
  const float4* g4 = (const float4*)gamma;
  const float4* b4 = (const float4*)beta;
  float4 g0 = g4[lane * 2], g1 = g4[lane * 2 + 1];
  float4 bb0 = b4[lane * 2], bb1 = b4[lane * 2 + 1];
  float4 y0, y1;
  y0.x = (x[0] - mu) * rs * g0.x + bb0.x;
  y0.y = (x[1] - mu) * rs * g0.y + bb0.y;
  y0.z = (x[2] - mu) * rs * g0.z + bb0.z;
  y0.w = (x[3] - mu) * rs * g0.w + bb0.w;
  y1.x = (x[4] - mu) * rs * g1.x + bb1.x;
  y1.y = (x[5] - mu) * rs * g1.y + bb1.y;
  y1.z = (x[6] - mu) * rs * g1.z + bb1.z;
  y1.w = (x[7] - mu) * rs * g1.w + bb1.w;
  float4* o4 = (float4*)(out + (size_t)row * 512);
  o4[lane * 2] = y0;
  o4[lane * 2 + 1] = y1;
}

// ---------- launch ----------
extern "C" void kernel_launch(void* const* d_in, const int* in_sizes, int n_in,
                              void* d_out, int out_size, void* d_ws, size_t ws_size,
                              hipStream_t stream) {
  (void)in_sizes; (void)n_in; (void)out_size; (void)ws_size;
  const float* inQ = (const float*)d_in[0];
  const float* inK = (const float*)d_in[1];
  const float* inV = (const float*)d_in[2];
  const float* Wq = (const float*)d_in[4];
  const float* Wk = (const float*)d_in[5];
  const float* Wv = (const float*)d_in[6];
  const float* Wo = (const float*)d_in[7];
  const float* gamma = (const float*)d_in[8];
  const float* beta = (const float*)d_in[9];

  float* out = (float*)d_out;
  float* attn = out + (size_t)4 * 2048 * 512;

  char* ws = (char*)d_ws;
  u16* Qp  = (u16*)(ws + 0);
  u16* Kp  = (u16*)(ws + 8388608);
  u16* Vp  = (u16*)(ws + 16777216);      // freed after transpose_v -> reused for invl
  u16* Vt  = (u16*)(ws + 25165824);
  u16* ctx = (u16*)(ws + 33554432);
  u16* Wbf = (u16*)(ws + 41943040);
  float* invl = (float*)(ws + 16777216); // 256 KB, overlaps dead Vp
  float* proj = (float*)(ws + 0);        // reuses Qp+Kp after attention
  u16* Xbf = (u16*)attn;

  cvt3<<<2048, 256, 0, stream>>>(inQ, inK, inV, Xbf, 1048576, 4194304);
  cvtW<<<256, 256, 0, stream>>>(Wq, Wk, Wv, Wo, Wbf, 65536, 262144);
  gemm_qkv<<<dim3(64, 4, 3), 256, 0, stream>>>(Xbf, Wbf, Qp);
  transpose_v<<<dim3(32, 8, 4), 256, 0, stream>>>(Vp, Vt);
  lsum_kernel<<<256, 512, 0, stream>>>(Qp, Kp, invl);
  attn_kernel<<<dim3(512), 512, 0, stream>>>(Qp, Kp, Vt, invl, attn, ctx);
  gemm_f32out<<<dim3(64, 4, 1), 256, 0, stream>>>(ctx, Wbf + (size_t)3 * 262144, proj);
  ln_kernel<<<2048, 256, 0, stream>>>(proj, inQ, gamma, beta, out);
}